// Round 12
// baseline (1210.177 us; speedup 1.0000x reference)
//
#include <hip/hip_runtime.h>
#include <hip/hip_bf16.h>
#include <hip/hip_fp16.h>
#include <stdint.h>

#define D_  256   // emb dim
#define FD_ 512   // feat dim
#define L_  5     // layers
#define EPS_ 1e-5f

// packed-tile format (R6-proven): tile = 128 rows x 32 k, stored as 4 k-planes
// (8 k each): plane = 128 rows x 16B + 64B pad = 2112B. tile = 8448B = 4224 sh.
#define PLANE_SH 1056
#define TILE_SH  4224

typedef unsigned short ushort_t;
typedef __attribute__((ext_vector_type(8))) _Float16 h8v;  // 8 f16 (MFMA frag)
typedef __attribute__((ext_vector_type(4))) float    f4v;  // MFMA C/D frag

// numerically-stable softplus == jnp.logaddexp(x, 0) — NATIVE exp/log (R11-proven)
__device__ __forceinline__ float sp(float x) {
    float t = __expf(-fabsf(x));            // native v_exp_f32
    return fmaxf(x, 0.f) + __logf(1.f + t); // native v_log_f32
}

__device__ __forceinline__ ushort_t f2h_bits(float v) {
    union { _Float16 h; ushort_t u; } c;
    c.h = (_Float16)v;
    return c.u;
}

__device__ __forceinline__ float h2f(ushort_t u) {
    union { ushort_t u; _Float16 h; } c;
    c.u = u;
    return (float)c.h;
}

// two f32 -> one u32 of 2xf16 (RTNE, matches f2h_bits everywhere else)
__device__ __forceinline__ uint32_t pk2(float a, float b) {
    return (uint32_t)f2h_bits(a) | ((uint32_t)f2h_bits(b) << 16);
}

// packed-f16 element offset for (row gm, col gn) with nKB = cols/32
__device__ __forceinline__ size_t pk_off(int gm, int gn, int nKB) {
    return ((size_t)(gm >> 7) * nKB + (gn >> 5)) * TILE_SH
         + (size_t)((gn >> 3) & 3) * PLANE_SH
         + (gm & 127) * 8 + (gn & 7);
}

// ---------------------------------------------------------------------------
// h16[i,d] = f16( x_emb1[atomics[i],d] + pos[i,:] @ x_emb2_w[:,d] + x_emb2_b[d] )
// ---------------------------------------------------------------------------
__global__ __launch_bounds__(256)
void init_h_kernel(const int* __restrict__ atomics, const float* __restrict__ pos,
                   const float* __restrict__ emb1, const float* __restrict__ w2,
                   const float* __restrict__ b2, ushort_t* __restrict__ h16, int N)
{
    int i = blockIdx.x;
    int d = threadIdx.x;
    int a = atomics[i];
    float p0 = pos[(size_t)i * 3 + 0];
    float p1 = pos[(size_t)i * 3 + 1];
    float p2 = pos[(size_t)i * 3 + 2];
    float v = emb1[(size_t)a * D_ + d]
            + p0 * w2[0 * D_ + d]
            + p1 * w2[1 * D_ + d]
            + p2 * w2[2 * D_ + d]
            + b2[d];
    h16[(size_t)i * D_ + d] = f2h_bits(v);
}

// ---------------------------------------------------------------------------
// CSR build (unordered segments; segment order irrelevant)
// ---------------------------------------------------------------------------
__global__ __launch_bounds__(256)
void hist_kernel(const int* __restrict__ dst, int* __restrict__ cnt, int E)
{
    int e = blockIdx.x * 256 + threadIdx.x;
    if (e < E) atomicAdd(&cnt[dst[e]], 1);
}

__global__ __launch_bounds__(256)
void alloc_kernel(const int* __restrict__ cnt, int* __restrict__ start,
                  int* __restrict__ cursor, int* __restrict__ total, int N)
{
    int i = blockIdx.x * 256 + threadIdx.x;
    if (i < N) {
        int s = atomicAdd(total, cnt[i]);
        start[i] = s;
        cursor[i] = s;
    }
}

__global__ __launch_bounds__(256)
void fill_kernel(const int* __restrict__ src, const int* __restrict__ dst,
                 const int* __restrict__ attr, int* __restrict__ cursor,
                 uint32_t* __restrict__ elist, int E)
{
    int e = blockIdx.x * 256 + threadIdx.x;
    if (e < E) {
        int p = atomicAdd(&cursor[dst[e]], 1);
        elist[p] = (uint32_t)src[e] | ((uint32_t)attr[e] << 30);
    }
}

// ---------------------------------------------------------------------------
// graph node ranges (batch is sorted): gstart[g]..gend[g]
// ---------------------------------------------------------------------------
__global__ __launch_bounds__(256)
void range_kernel(const int* __restrict__ batch, int* __restrict__ gstart,
                  int* __restrict__ gend, int N)
{
    int i = blockIdx.x * 256 + threadIdx.x;
    if (i >= N) return;
    int b = batch[i];
    if (i == 0 || batch[i - 1] != b) gstart[b] = i;
    if (i == N - 1 || batch[i + 1] != b) gend[b] = i + 1;
}

// ---------------------------------------------------------------------------
// act16 [R24]: hact = f16( sp( BN-affine(h16) ) ), 16 ch/thread (32B loads)
// ---------------------------------------------------------------------------
__global__ __launch_bounds__(256)
void act16_kernel(const ushort_t* __restrict__ h16, ushort_t* __restrict__ hact,
                  const float* __restrict__ bnsum, const float* __restrict__ gamma,
                  const float* __restrict__ beta, long long total16, float invN)
{
    __shared__ float ssc[256], ssh[256];
    int t = threadIdx.x;
    {
        float mean = bnsum[t] * invN;
        float var = bnsum[D_ + t] * invN - mean * mean;
        float sc = gamma[t] * rsqrtf(fmaxf(var, 0.f) + EPS_);
        ssc[t] = sc;
        ssh[t] = beta[t] - mean * sc;
    }
    __syncthreads();
    long long idx = (long long)blockIdx.x * 256 + t;
    if (idx >= total16) return;
    int c0 = (int)((idx * 16) & 255);
    uint4 in0 = *(const uint4*)(h16 + idx * 16);
    uint4 in1 = *(const uint4*)(h16 + idx * 16 + 8);
    ushort_t* ip0 = (ushort_t*)&in0;
    ushort_t* ip1 = (ushort_t*)&in1;
    ushort_t ov[16];
#pragma unroll
    for (int j = 0; j < 8; ++j)
        ov[j] = f2h_bits(sp(h2f(ip0[j]) * ssc[c0 + j] + ssh[c0 + j]));
#pragma unroll
    for (int j = 0; j < 8; ++j)
        ov[8 + j] = f2h_bits(sp(h2f(ip1[j]) * ssc[c0 + 8 + j] + ssh[c0 + 8 + j]));
    *(uint4*)(hact + idx * 16)     = *(uint4*)&ov[0];
    *(uint4*)(hact + idx * 16 + 8) = *(uint4*)&ov[8];
}

// ---------------------------------------------------------------------------
// gather2 [R28-proven]: scalar control plane + branch-skipped loads
// ---------------------------------------------------------------------------
__global__ __launch_bounds__(256)
void gather2_kernel(const ushort_t* __restrict__ hact, const uint32_t* __restrict__ elist,
                    const int* __restrict__ start, const int* __restrict__ cnt,
                    const float* __restrict__ ee_l, ushort_t* __restrict__ aggP, int N)
{
    int t = threadIdx.x;
    int d0 = (t & 127) * 2;
    // wave-uniform first row of this half (t>>7 is uniform within a wave)
    int ib = __builtin_amdgcn_readfirstlane(blockIdx.x * 8 + (t >> 7) * 4);
    float2 e0 = *(const float2*)(ee_l + d0);        // bond 0 pair
    float2 e1 = *(const float2*)(ee_l + D_ + d0);   // bond 1 / self-loop pair
    int sbase[4], sdeg[4];
    float ax[4], ay[4];
    int mdeg = 0;
#pragma unroll
    for (int r = 0; r < 4; ++r) {
        int i = ib + r;
        sbase[r] = 0; sdeg[r] = 0; ax[r] = 0.f; ay[r] = 0.f;
        if (i < N) {                       // uniform branch
            sbase[r] = start[i];           // scalar addr -> s_load
            sdeg[r]  = cnt[i];
            uint32_t hv = *(const uint32_t*)(hact + (size_t)i * D_ + d0);
            ax[r] = h2f((ushort_t)hv) + e1.x;
            ay[r] = h2f((ushort_t)(hv >> 16)) + e1.y;
            mdeg = (sdeg[r] > mdeg) ? sdeg[r] : mdeg;
        }
    }
    for (int j = 0; j < mdeg; j += 2) {
        uint32_t pA[4], pB[4];
#pragma unroll
        for (int r = 0; r < 4; ++r) {      // guarded scalar loads (s_cbranch)
            if (j     < sdeg[r]) pA[r] = elist[sbase[r] + j];
            if (j + 1 < sdeg[r]) pB[r] = elist[sbase[r] + j + 1];
        }
        uint32_t hvA[4], hvB[4];
#pragma unroll
        for (int r = 0; r < 4; ++r)        // guarded vector loads, batched issue
            if (j < sdeg[r])
                hvA[r] = *(const uint32_t*)(hact + (size_t)(pA[r] & 0x3FFFFFFF) * D_ + d0);
#pragma unroll
        for (int r = 0; r < 4; ++r)
            if (j + 1 < sdeg[r])
                hvB[r] = *(const uint32_t*)(hact + (size_t)(pB[r] & 0x3FFFFFFF) * D_ + d0);
#pragma unroll
        for (int r = 0; r < 4; ++r) {
            if (j < sdeg[r]) {             // uniform branch
                bool b1 = (pA[r] >> 30) != 0;   // scalar condition
                ax[r] += h2f((ushort_t)hvA[r]) + (b1 ? e1.x : e0.x);
                ay[r] += h2f((ushort_t)(hvA[r] >> 16)) + (b1 ? e1.y : e0.y);
            }
            if (j + 1 < sdeg[r]) {
                bool b1 = (pB[r] >> 30) != 0;
                ax[r] += h2f((ushort_t)hvB[r]) + (b1 ? e1.x : e0.x);
                ay[r] += h2f((ushort_t)(hvB[r] >> 16)) + (b1 ? e1.y : e0.y);
            }
        }
    }
#pragma unroll
    for (int r = 0; r < 4; ++r) {
        int i = ib + r;
        if (i < N) {
            size_t o = pk_off(i, d0, 8);   // even -> 4B-aligned u32 slot
            *(uint32_t*)(aggP + o) = pk2(ax[r], ay[r]);
        }
    }
}

// ---------------------------------------------------------------------------
// pool_bn [R21]: graph-mean of BN-affine(h16) -> packed f16 (feeds feat gemm).
// ---------------------------------------------------------------------------
__global__ __launch_bounds__(256)
void pool_bn_kernel(const ushort_t* __restrict__ h16, const float* __restrict__ bnsum,
                    const float* __restrict__ gamma, const float* __restrict__ beta,
                    const int* __restrict__ gstart, const int* __restrict__ gend,
                    ushort_t* __restrict__ poolP, float invN)
{
    int g = blockIdx.x;
    int d = threadIdx.x;
    float mean = bnsum[d] * invN;
    float var = bnsum[D_ + d] * invN - mean * mean;
    float sc = gamma[d] * rsqrtf(fmaxf(var, 0.f) + EPS_);
    float sh = beta[d] - mean * sc;
    int s0 = gstart[g], s1 = gend[g];
    float acc = 0.f;
    int i = s0;
    for (; i + 4 <= s1; i += 4) {
        float a0 = h2f(h16[(size_t)(i + 0) * D_ + d]);
        float a1 = h2f(h16[(size_t)(i + 1) * D_ + d]);
        float a2 = h2f(h16[(size_t)(i + 2) * D_ + d]);
        float a3 = h2f(h16[(size_t)(i + 3) * D_ + d]);
        acc += (a0 + a1) + (a2 + a3);
    }
    for (; i < s1; ++i)
        acc += h2f(h16[(size_t)i * D_ + d]);
    int cnt = s1 - s0;
    float mval = (cnt > 0) ? (sc * acc / (float)cnt + sh) : 0.f;
    poolP[pk_off(g, d, 8)] = f2h_bits(mval);
}

// ---------------------------------------------------------------------------
// weight pack (R16): W fp32 [K][N] -> SINGLE f16 tiles (nb, kb), row = col n
// ---------------------------------------------------------------------------
__global__ __launch_bounds__(256)
void convert_w_pack(const float* __restrict__ W, ushort_t* __restrict__ dh,
                    int N, int nKB)
{
    int kb = blockIdx.x, nb = blockIdx.y;
    int n = threadIdx.x >> 1, half = threadIdx.x & 1;
#pragma unroll
    for (int j = 0; j < 2; ++j) {
        int kq = half * 2 + j;
        size_t o = (size_t)(nb * nKB + kb) * TILE_SH + kq * PLANE_SH + n * 8;
#pragma unroll
        for (int jj = 0; jj < 8; ++jj) {
            float w = W[(size_t)(kb * 32 + kq * 8 + jj) * N + nb * 128 + n];
            dh[o + jj] = f2h_bits(w);
        }
    }
}

// ---------------------------------------------------------------------------
// fused_mlp_kernel [R29]: R24 schedule at 32-ROW BLOCKS for FULL OCCUPANCY.
// R24/25/27 all pinned at 16 waves/CU (64KB LDS cap) with MfmaUtil 21 /
// VALUBusy 40 -> latency-floored; the untried axis was occupancy. 32-row
// block: Tl = 32x512 f16 = 32KB, acc1[4][2]+acc2[2][2] fit the 64-VGPR
// class -> __launch_bounds__(512,8) = 4 blocks/CU x 8 waves = 32 waves/CU
// (2x TLP). Cost: W1/W2 re-read per block (L2-resident) and 0.75 loads/MFMA
// (was 0.5) — acceptable for a latency-bound kernel.
// Packed-T layout (32-row tiles): tile = 1024 sh, plane = 256 sh;
// n = w*64 + nt*16 + kq*4 + rr -> tile w*2+(nt>>1), plane (nt&1)*2+(kq>>1),
// byte-sub (kq&1)*4+rr; row m = mt*16+fr (mt 0..1).
// ---------------------------------------------------------------------------
__global__ __launch_bounds__(512, 8)
void fused_mlp_kernel(const ushort_t* __restrict__ APK,
                      const ushort_t* __restrict__ W1P,
                      const ushort_t* __restrict__ W2P,
                      const float* __restrict__ b1,
                      const float* __restrict__ b2,
                      ushort_t* __restrict__ Hout,
                      float* __restrict__ bnsum,
                      int m)
{
    __shared__ ushort_t Tl[16384];   // 32 rows x 512 cols packed f16 = 32 KB

    int rb = blockIdx.x;             // 32-row block
    int tid = threadIdx.x, w = tid >> 6, lane = tid & 63;
    int fr = lane & 15, kq = lane >> 4;

    // ---- stage 1 (swapped): T cols [w*64, w*64+64), rows rb*32..+32 ----
    const ushort_t* aT = APK + (size_t)(rb >> 2) * (8 * TILE_SH)
                       + (size_t)kq * PLANE_SH + (size_t)((rb & 3) * 32 + fr) * 8;
    const ushort_t* bT = W1P + (size_t)(w >> 1) * (8 * TILE_SH)
                       + (size_t)kq * PLANE_SH + (size_t)((w & 1) * 64 + fr) * 8;

    f4v acc1[4][2];   // [nt][mt]
#pragma unroll
    for (int i = 0; i < 4; ++i)
#pragma unroll
        for (int j = 0; j < 2; ++j)
            acc1[i][j] = (f4v){0.f, 0.f, 0.f, 0.f};

    for (int kb = 0; kb < 8; ++kb) {
        h8v Af[2], Wf[4];
#pragma unroll
        for (int t = 0; t < 2; ++t)
            Af[t] = *(const h8v*)(aT + (size_t)kb * TILE_SH + t * 128);
#pragma unroll
        for (int t = 0; t < 4; ++t)
            Wf[t] = *(const h8v*)(bT + (size_t)kb * TILE_SH + t * 128);
        __builtin_amdgcn_s_setprio(1);
#pragma unroll
        for (int nt = 0; nt < 4; ++nt)
#pragma unroll
            for (int mt = 0; mt < 2; ++mt)
                acc1[nt][mt] = __builtin_amdgcn_mfma_f32_16x16x32_f16(
                    Wf[nt], Af[mt], acc1[nt][mt], 0, 0, 0);
        __builtin_amdgcn_s_setprio(0);
    }

    // T -> LDS: lane holds T[m = mt*16+fr][n = w*64 + nt*16 + kq*4 + rr].
#pragma unroll
    for (int nt = 0; nt < 4; ++nt) {
        float4 b1v = *(const float4*)(b1 + w * 64 + nt * 16 + kq * 4);
        int baseu = (w * 2 + (nt >> 1)) * 1024
                  + ((nt & 1) * 2 + (kq >> 1)) * 256
                  + (kq & 1) * 4;
#pragma unroll
        for (int mt = 0; mt < 2; ++mt) {
            uint2 val;
            val.x = pk2(sp(acc1[nt][mt][0] + b1v.x), sp(acc1[nt][mt][1] + b1v.y));
            val.y = pk2(sp(acc1[nt][mt][2] + b1v.z), sp(acc1[nt][mt][3] + b1v.w));
            *(uint2*)(Tl + baseu + (mt * 16 + fr) * 8) = val;
        }
    }
    __syncthreads();

    // ---- stage 2: cols [w*32, w*32+32) of 256 ----
    const ushort_t* wT = W2P + (size_t)(w >> 2) * (16 * TILE_SH)
                       + (size_t)kq * PLANE_SH + (size_t)((w & 3) * 32 + fr) * 8;

    f4v acc2[2][2];
#pragma unroll
    for (int i = 0; i < 2; ++i)
#pragma unroll
        for (int j = 0; j < 2; ++j)
            acc2[i][j] = (f4v){0.f, 0.f, 0.f, 0.f};

    for (int kb = 0; kb < 16; ++kb) {
        h8v Tf[2], Wf[2];
#pragma unroll
        for (int t = 0; t < 2; ++t)
            Tf[t] = *(const h8v*)(Tl + kb * 1024 + kq * 256 + (fr + t * 16) * 8);
#pragma unroll
        for (int t = 0; t < 2; ++t)
            Wf[t] = *(const h8v*)(wT + (size_t)kb * TILE_SH + t * 128);
        __builtin_amdgcn_s_setprio(1);
#pragma unroll
        for (int rt = 0; rt < 2; ++rt)
#pragma unroll
            for (int ct = 0; ct < 2; ++ct)
                acc2[rt][ct] = __builtin_amdgcn_mfma_f32_16x16x32_f16(
                    Tf[rt], Wf[ct], acc2[rt][ct], 0, 0, 0);
        __builtin_amdgcn_s_setprio(0);
    }

    // ---- epilogue: row-major f16 h + bn partial sums ----
    int gm0 = rb * 32 + kq * 4;
#pragma unroll
    for (int ct = 0; ct < 2; ++ct) {
        int gn = w * 32 + ct * 16 + fr;
        float bv = b2[gn];
        float s = 0.f, ss = 0.f;
#pragma unroll
        for (int rt = 0; rt < 2; ++rt)
#pragma unroll
            for (int rr = 0; rr < 4; ++rr) {
                int gm = gm0 + rt * 16 + rr;
                if (gm < m) {
                    float v = acc2[rt][ct][rr] + bv;
                    Hout[(size_t)gm * D_ + gn] = f2h_bits(v);
                    s += v;
                    ss += v * v;
                }
            }
        s  += __shfl_xor(s, 16);  s  += __shfl_xor(s, 32);
        ss += __shfl_xor(ss, 16); ss += __shfl_xor(ss, 32);
        if (kq == 0) {
            atomicAdd(&bnsum[gn], s);
            atomicAdd(&bnsum[D_ + gn], ss);
        }
    }
}

// ---------------------------------------------------------------------------
// gemm_p16<EPI> [R19 form]  EPI 3: fp32 row-major Cout = A@B + bias (no act)
// ---------------------------------------------------------------------------
template <int EPI>
__global__ __launch_bounds__(256, 3)
void gemm_p16(const ushort_t* __restrict__ APK, const ushort_t* __restrict__ BPK,
              const float* __restrict__ bias,
              ushort_t* __restrict__ Tout, float* __restrict__ Cout,
              float* __restrict__ bnsum, const int* __restrict__ batch,
              int m, int N, int nKB)
{
    const int NB = N >> 7;
    const int mb = (m + 127) >> 7;
    int id = blockIdx.x;
    int grp = id / (8 * NB);
    int rem = id - grp * 8 * NB;
    int nb = rem >> 3;
    int rb = grp * 8 + (rem & 7);
    if (rb >= mb) return;   // uniform early-out (tail row-group)

    int tid = threadIdx.x, wave = tid >> 6, lane = tid & 63;
    int wr = wave >> 1, wc = wave & 1;
    int fr = lane & 15, kq = lane >> 4;

    const ushort_t* aP = APK + (size_t)rb * nKB * TILE_SH
                       + (size_t)kq * PLANE_SH + (size_t)(wr * 64 + fr) * 8;
    const ushort_t* bP = BPK + (size_t)nb * nKB * TILE_SH
                       + (size_t)kq * PLANE_SH + (size_t)(wc * 64 + fr) * 8;

    f4v acc[4][4];
#pragma unroll
    for (int i = 0; i < 4; ++i)
#pragma unroll
        for (int j = 0; j < 4; ++j)
            acc[i][j] = (f4v){0.f, 0.f, 0.f, 0.f};

    h8v Fa[4], Fb[4], Ga[4], Gb[4];

#define LOADF(dA, dB, kbi)                                                   \
    {   const ushort_t* ap_ = aP + (size_t)(kbi) * TILE_SH;                  \
        const ushort_t* bp_ = bP + (size_t)(kbi) * TILE_SH;                  \
        _Pragma("unroll")                                                    \
        for (int t = 0; t < 4; ++t) {                                        \
            dA[t] = *(const h8v*)(ap_ + t * 128);                            \
            dB[t] = *(const h8v*)(bp_ + t * 128);                            \
        } }

#define MFMA16(sA, sB)                                                       \
    {   __builtin_amdgcn_s_setprio(1);                                       \
        _Pragma("unroll")                                                    \
        for (int rt = 0; rt < 4; ++rt)                                       \
            _Pragma("unroll")                                                \
            for (int ct = 0; ct < 4; ++ct)                                   \
                acc[rt][ct] = __builtin_amdgcn_mfma_f32_16x16x32_f16(        \
                    sA[rt], sB[ct], acc[rt][ct], 0, 0, 0);                   \
        __builtin_amdgcn_s_setprio(0); }

    LOADF(Fa, Fb, 0);
    for (int kb = 0; kb < nKB; kb += 2) {
        LOADF(Ga, Gb, kb + 1);
        MFMA16(Fa, Fb);
        if (kb + 2 < nKB) LOADF(Fa, Fb, kb + 2);
        MFMA16(Ga, Gb);
    }
#undef LOADF
#undef MFMA16

    int gm00 = rb * 128 + wr * 64 + kq * 4;
    int gn0  = nb * 128 + wc * 64 + fr;
    int nKBo = N >> 5;
    size_t tileRow = (size_t)(rb * nKBo + nb * 4 + wc * 2) * TILE_SH
                   + (size_t)((wr * 64 + kq * 4) * 8 + (fr & 7));
#pragma unroll
    for (int ct = 0; ct < 4; ++ct) {
        int gn = gn0 + ct * 16;
        float bv = bias[gn];
        float s = 0.f, ss = 0.f;
        size_t cb = tileRow + (size_t)(ct >> 1) * TILE_SH
                  + (size_t)((2 * ct + (fr >> 3)) & 3) * PLANE_SH;
#pragma unroll
        for (int rt = 0; rt < 4; ++rt) {
            if (EPI == 2) {
                int bp = -1; float run = 0.f;
#pragma unroll
                for (int rr = 0; rr < 4; ++rr) {
                    int gm = gm00 + rt * 16 + rr;
                    if (gm >= m) continue;
                    float v = acc[rt][ct][rr] + bv;
                    int bg = batch[gm];
                    if (bg == bp) { run += v; }
                    else {
                        if (bp >= 0) atomicAdd(&Cout[(size_t)bp * N + gn], run);
                        bp = bg; run = v;
                    }
                }
                if (bp >= 0) atomicAdd(&Cout[(size_t)bp * N + gn], run);
            } else {
#pragma unroll
                for (int rr = 0; rr < 4; ++rr) {
                    int gm = gm00 + rt * 16 + rr;
                    if (gm >= m) continue;
                    float v = acc[rt][ct][rr] + bv;
                    if (EPI == 0) {
                        Tout[cb + (rt * 16 + rr) * 8] = f2h_bits(sp(v));
                    } else if (EPI == 1) {
                        Tout[(size_t)gm * N + gn] = f2h_bits(v);
                        s += v;
                        ss += v * v;
                    } else {  // EPI == 3: fp32 row-major, no activation
                        Cout[(size_t)gm * N + gn] = v;
                    }
                }
            }
        }
        if (EPI == 1) {
            s  += __shfl_xor(s, 16);  s  += __shfl_xor(s, 32);
            ss += __shfl_xor(ss, 16); ss += __shfl_xor(ss, 32);
            if (kq == 0) {
                atomicAdd(&bnsum[gn], s);
                atomicAdd(&bnsum[D_ + gn], ss);
            }
        }
    }
}

// ---------------------------------------------------------------------------
// fp32 GEMM for the small head: C = softplus(A @ W + bias)
// ---------------------------------------------------------------------------
#define BM 64
#define BN 64
#define BK 16

__global__ __launch_bounds__(256)
void gemm_head(const float* __restrict__ A, const float* __restrict__ W,
               const float* __restrict__ bias, float* __restrict__ C,
               int M, int N, int K)
{
    __shared__ float As[BK][BM + 4];
    __shared__ float Ws[BK][BN + 4];

    int tid = threadIdx.x;
    int bm = blockIdx.y * BM;
    int bn = blockIdx.x * BN;
    int tx = tid & 15;
    int ty = tid >> 4;

    float acc[4][4] = {};

    int a_m = tid >> 2;
    int a_k = (tid & 3) * 4;
    int w_k = tid >> 4;
    int w_n = (tid & 15) * 4;

    for (int k0 = 0; k0 < K; k0 += BK) {
        int gm = bm + a_m;
        float4 av = make_float4(0.f, 0.f, 0.f, 0.f);
        if (gm < M)
            av = *(const float4*)(A + (size_t)gm * K + k0 + a_k);
        As[a_k + 0][a_m] = av.x;
        As[a_k + 1][a_m] = av.y;
        As[a_k + 2][a_m] = av.z;
        As[a_k + 3][a_m] = av.w;

        float4 wv = *(const float4*)(W + (size_t)(k0 + w_k) * N + bn + w_n);
        *(float4*)&Ws[w_k][w_n] = wv;

        __syncthreads();

#pragma unroll
        for (int k = 0; k < BK; ++k) {
            float4 a4 = *(const float4*)&As[k][ty * 4];
            float4 b4 = *(const float4*)&Ws[k][tx * 4];
            float a[4] = {a4.x, a4.y, a4.z, a4.w};
            float b[4] = {b4.x, b4.y, b4.z, b4.w};
#pragma unroll
            for (int i = 0; i < 4; ++i)
#pragma unroll
                for (int j = 0; j < 4; ++j)
                    acc[i][j] += a[i] * b[j];
        }
        __syncthreads();
    }

#pragma unroll
    for (int i = 0; i < 4; ++i) {
        int gm = bm + ty * 4 + i;
        if (gm >= M) continue;
#pragma unroll
        for (int j = 0; j < 4; ++j) {
            int gn = bn + tx * 4 + j;
            C[(size_t)gm * N + gn] = sp(acc[i][j] + bias[gn]);
        }
    }
}

__global__ __launch_bounds__(256)
void head2_kernel(const float* __restrict__ hid, const float* __restrict__ w2,
                  const float* __restrict__ b2, float* __restrict__ out, int G)
{
    __shared__ float red[256];
    int g = blockIdx.x;
    int t = threadIdx.x;
    float v = hid[(size_t)g * 256 + t] * w2[t];
    red[t] = v;
    __syncthreads();
    for (int s = 128; s > 0; s >>= 1) {
        if (t < s) red[t] += red[t + s];
        __syncthreads();
    }
    if (t == 0) out[g] = red[0] + b2[0];
}

// ---------------------------------------------------------------------------
extern "C" void kernel_launch(void* const* d_in, const int* in_sizes, int n_in,
                              void* d_out, int out_size, void* d_ws, size_t ws_size,
                              hipStream_t stream)
{
    const int N = in_sizes[0];
    const int E = in_sizes[3];
    const int G = out_size;

    const int*   atomics  = (const int*)d_in[0];
    const float* pos      = (const float*)d_in[1];
    const int*   eidx     = (const int*)d_in[2];
    const int*   eattr    = (const int*)d_in[3];
    const int*   batch    = (const int*)d_in[4];
    const float* x_emb1   = (const float*)d_in[5];
    const float* x_emb2_w = (const float*)d_in[6];
    const float* x_emb2_b = (const float*)d_in[7];
    const float* edge_emb = (const float*)d_in[8];
    const float* mlp_w1   = (const float*)d_in[9];
    const float* mlp_b1   = (const float*)d_in[10];
    const float* mlp_w2   = (const float*)d_in[11];
    const float* mlp_b2   = (const float*)d_in[12];
    const float* bn_g     = (const float*)d_in[13];
    const float* bn_b     = (const float*)d_in[14];
    const float* feat_w   = (const float*)d_in[15];
    const float* feat_b   = (const float*)d_in[16];
    const float* head_w1  = (const float*)d_in[17];
    const float* head_b1  = (const float*)d_in[18];
    const float* head_w2  = (const float*)d_in[19];
    const float* head_b2  = (const float*)d_in[20];
    float* out = (float*)d_out;

    const int* src = eidx;
    const int* dst = eidx + E;

    char* ws = (char*)d_ws;
    size_t off = 0;
    auto carve = [&](size_t bytes) {
        void* p = ws + off;
        off += (bytes + 255) & ~(size_t)255;
        return p;
    };

    const int nRB = (N + 127) / 128;           // 128-row tiles
    const int nGB = (G + 127) / 128;           // 128-row tiles of pooled

    // ---- fixed carve (~170 MB) ----
    ushort_t* h16  = (ushort_t*)carve((size_t)N * D_ * 2);             // 51.2 MB
    ushort_t* hact = (ushort_t*)carve((size_t)N * D_ * 2);             // 51.2 MB
    ushort_t* aggP = (ushort_t*)carve((size_t)nRB * 8 * TILE_SH * 2);  // 52.9 MB
    const size_t WTILES = 32 * TILE_SH;
    ushort_t* w1P = (ushort_t*)carve((size_t)L_ * WTILES * 2);
    ushort_t* w2P = (ushort_t*)carve((size_t)L_ * WTILES * 2);
    ushort_t* fP  = (ushort_t*)carve(WTILES * 2);
    float* bnsum  = (float*)carve(2 * D_ * 4);
    float* gfeat  = (float*)carve((size_t)G * FD_ * 4);                // 8.2 MB
    float* hid    = (float*)carve((size_t)G * (FD_ / 2) * 4);
    ushort_t* poolP = (ushort_t*)carve((size_t)nGB * 8 * TILE_SH * 2); // 2.2 MB
    int* gstart  = (int*)carve((size_t)G * 4);
    int* gend    = (int*)carve((size_t)G * 4);
    // CSR buffers (~5 MB)
    int* cnt_i   = (int*)carve((size_t)N * 4);
    int* start_i = (int*)carve((size_t)N * 4);
    int* cursor  = (int*)carve((size_t)N * 4);
    int* total   = (int*)carve(4);
    uint32_t* elist = (uint32_t*)carve((size_t)E * 4);

    const float invN = 1.f / (float)N;

    // ---- CSR build (once per launch, reused all 5 layers) ----
    hipMemsetAsync(cnt_i, 0, (size_t)N * 4, stream);
    hipMemsetAsync(total, 0, 4, stream);
    hipMemsetAsync(gstart, 0, (size_t)G * 4, stream);
    hipMemsetAsync(gend, 0, (size_t)G * 4, stream);
    hist_kernel<<<(E + 255) / 256, 256, 0, stream>>>(dst, cnt_i, E);
    alloc_kernel<<<(N + 255) / 256, 256, 0, stream>>>(cnt_i, start_i, cursor, total, N);
    fill_kernel<<<(E + 255) / 256, 256, 0, stream>>>(src, dst, eattr, cursor, elist, E);
    range_kernel<<<(N + 255) / 256, 256, 0, stream>>>(batch, gstart, gend, N);

    // ---- one-time weight packing (single f16) ----
    for (int l = 0; l < L_; ++l) {
        convert_w_pack<<<dim3(8, 4), 256, 0, stream>>>(
            mlp_w1 + (size_t)l * D_ * FD_, w1P + (size_t)l * WTILES, FD_, 8);
        convert_w_pack<<<dim3(16, 2), 256, 0, stream>>>(
            mlp_w2 + (size_t)l * FD_ * D_, w2P + (size_t)l * WTILES, D_, 16);
    }
    convert_w_pack<<<dim3(8, 4), 256, 0, stream>>>(feat_w, fP, FD_, 8);

    init_h_kernel<<<N, 256, 0, stream>>>(atomics, pos, x_emb1, x_emb2_w, x_emb2_b, h16, N);

    const long long total16 = (long long)N * D_ / 16;
    const int ACTB = (int)((total16 + 255) / 256);
    const int GB8 = (N + 7) / 8;
    const int FB  = (N + 31) / 32;             // fused 32-row blocks

    for (int l = 0; l < L_; ++l) {
        const float* ee_l = edge_emb + (size_t)l * 2 * D_;
        const ushort_t* gsrc = h16;
        if (l > 0) {
            act16_kernel<<<ACTB, 256, 0, stream>>>(h16, hact, bnsum,
                bn_g + (size_t)(l - 1) * D_, bn_b + (size_t)(l - 1) * D_,
                total16, invN);
            gsrc = hact;
        }
        gather2_kernel<<<GB8, 256, 0, stream>>>(gsrc, elist, start_i, cnt_i,
                                                ee_l, aggP, N);

        hipMemsetAsync(bnsum, 0, 2 * D_ * 4, stream);
        fused_mlp_kernel<<<FB, 512, 0, stream>>>(
            aggP, w1P + (size_t)l * WTILES, w2P + (size_t)l * WTILES,
            mlp_b1 + (size_t)l * FD_, mlp_b2 + (size_t)l * D_,
            h16, bnsum, N);
    }

    // ---- pool-first feat path: gfeat = mean_g(BN(h16)) @ feat_w + feat_b ----
    pool_bn_kernel<<<G, 256, 0, stream>>>(h16, bnsum, bn_g + (size_t)(L_ - 1) * D_,
                                          bn_b + (size_t)(L_ - 1) * D_,
                                          gstart, gend, poolP, invN);
    auto swgrid = [](int mb, int NBc) { return ((mb + 7) / 8) * 8 * NBc; };
    gemm_p16<3><<<swgrid(nGB, 4), 256, 0, stream>>>(
        poolP, fP, feat_b, nullptr, gfeat, nullptr, nullptr, G, FD_, 8);

    // ---- head ----
    gemm_head<<<dim3((FD_ / 2) / BN, (G + BM - 1) / BM), 256, 0, stream>>>(
        gfeat, head_w1, head_b1, hid, G, FD_ / 2, FD_);
    head2_kernel<<<G, 256, 0, stream>>>(hid, head_w2, head_b2, out, G);
}

// Round 13
// 1138.601 us; speedup vs baseline: 1.0629x; 1.0629x over previous
//
#include <hip/hip_runtime.h>
#include <hip/hip_bf16.h>
#include <hip/hip_fp16.h>
#include <stdint.h>

#define D_  256   // emb dim
#define FD_ 512   // feat dim
#define L_  5     // layers
#define EPS_ 1e-5f

// packed-tile format (R6-proven): tile = 128 rows x 32 k, stored as 4 k-planes
// (8 k each): plane = 128 rows x 16B + 64B pad = 2112B. tile = 8448B = 4224 sh.
#define PLANE_SH 1056
#define TILE_SH  4224

typedef unsigned short ushort_t;
typedef __attribute__((ext_vector_type(8))) _Float16 h8v;  // 8 f16 (MFMA frag)
typedef __attribute__((ext_vector_type(4))) float    f4v;  // MFMA C/D frag

// numerically-stable softplus == jnp.logaddexp(x, 0) — NATIVE exp/log (R11-proven)
__device__ __forceinline__ float sp(float x) {
    float t = __expf(-fabsf(x));            // native v_exp_f32
    return fmaxf(x, 0.f) + __logf(1.f + t); // native v_log_f32
}

__device__ __forceinline__ ushort_t f2h_bits(float v) {
    union { _Float16 h; ushort_t u; } c;
    c.h = (_Float16)v;
    return c.u;
}

__device__ __forceinline__ float h2f(ushort_t u) {
    union { ushort_t u; _Float16 h; } c;
    c.u = u;
    return (float)c.h;
}

// two f32 -> one u32 of 2xf16 (RTNE, matches f2h_bits everywhere else)
__device__ __forceinline__ uint32_t pk2(float a, float b) {
    return (uint32_t)f2h_bits(a) | ((uint32_t)f2h_bits(b) << 16);
}

// packed-f16 element offset for (row gm, col gn) with nKB = cols/32
__device__ __forceinline__ size_t pk_off(int gm, int gn, int nKB) {
    return ((size_t)(gm >> 7) * nKB + (gn >> 5)) * TILE_SH
         + (size_t)((gn >> 3) & 3) * PLANE_SH
         + (gm & 127) * 8 + (gn & 7);
}

// ---------------------------------------------------------------------------
// h16[i,d] = f16( x_emb1[atomics[i],d] + pos[i,:] @ x_emb2_w[:,d] + x_emb2_b[d] )
// ---------------------------------------------------------------------------
__global__ __launch_bounds__(256)
void init_h_kernel(const int* __restrict__ atomics, const float* __restrict__ pos,
                   const float* __restrict__ emb1, const float* __restrict__ w2,
                   const float* __restrict__ b2, ushort_t* __restrict__ h16, int N)
{
    int i = blockIdx.x;
    int d = threadIdx.x;
    int a = atomics[i];
    float p0 = pos[(size_t)i * 3 + 0];
    float p1 = pos[(size_t)i * 3 + 1];
    float p2 = pos[(size_t)i * 3 + 2];
    float v = emb1[(size_t)a * D_ + d]
            + p0 * w2[0 * D_ + d]
            + p1 * w2[1 * D_ + d]
            + p2 * w2[2 * D_ + d]
            + b2[d];
    h16[(size_t)i * D_ + d] = f2h_bits(v);
}

// ---------------------------------------------------------------------------
// CSR build (unordered segments; segment order irrelevant)
// ---------------------------------------------------------------------------
__global__ __launch_bounds__(256)
void hist_kernel(const int* __restrict__ dst, int* __restrict__ cnt, int E)
{
    int e = blockIdx.x * 256 + threadIdx.x;
    if (e < E) atomicAdd(&cnt[dst[e]], 1);
}

__global__ __launch_bounds__(256)
void alloc_kernel(const int* __restrict__ cnt, int* __restrict__ start,
                  int* __restrict__ cursor, int* __restrict__ total, int N)
{
    int i = blockIdx.x * 256 + threadIdx.x;
    if (i < N) {
        int s = atomicAdd(total, cnt[i]);
        start[i] = s;
        cursor[i] = s;
    }
}

__global__ __launch_bounds__(256)
void fill_kernel(const int* __restrict__ src, const int* __restrict__ dst,
                 const int* __restrict__ attr, int* __restrict__ cursor,
                 uint32_t* __restrict__ elist, int E)
{
    int e = blockIdx.x * 256 + threadIdx.x;
    if (e < E) {
        int p = atomicAdd(&cursor[dst[e]], 1);
        elist[p] = (uint32_t)src[e] | ((uint32_t)attr[e] << 30);
    }
}

// ---------------------------------------------------------------------------
// graph node ranges (batch is sorted): gstart[g]..gend[g]
// ---------------------------------------------------------------------------
__global__ __launch_bounds__(256)
void range_kernel(const int* __restrict__ batch, int* __restrict__ gstart,
                  int* __restrict__ gend, int N)
{
    int i = blockIdx.x * 256 + threadIdx.x;
    if (i >= N) return;
    int b = batch[i];
    if (i == 0 || batch[i - 1] != b) gstart[b] = i;
    if (i == N - 1 || batch[i + 1] != b) gend[b] = i + 1;
}

// ---------------------------------------------------------------------------
// act16 [R24]: hact = f16( sp( BN-affine(h16) ) ), 16 ch/thread (32B loads)
// ---------------------------------------------------------------------------
__global__ __launch_bounds__(256)
void act16_kernel(const ushort_t* __restrict__ h16, ushort_t* __restrict__ hact,
                  const float* __restrict__ bnsum, const float* __restrict__ gamma,
                  const float* __restrict__ beta, long long total16, float invN)
{
    __shared__ float ssc[256], ssh[256];
    int t = threadIdx.x;
    {
        float mean = bnsum[t] * invN;
        float var = bnsum[D_ + t] * invN - mean * mean;
        float sc = gamma[t] * rsqrtf(fmaxf(var, 0.f) + EPS_);
        ssc[t] = sc;
        ssh[t] = beta[t] - mean * sc;
    }
    __syncthreads();
    long long idx = (long long)blockIdx.x * 256 + t;
    if (idx >= total16) return;
    int c0 = (int)((idx * 16) & 255);
    uint4 in0 = *(const uint4*)(h16 + idx * 16);
    uint4 in1 = *(const uint4*)(h16 + idx * 16 + 8);
    ushort_t* ip0 = (ushort_t*)&in0;
    ushort_t* ip1 = (ushort_t*)&in1;
    ushort_t ov[16];
#pragma unroll
    for (int j = 0; j < 8; ++j)
        ov[j] = f2h_bits(sp(h2f(ip0[j]) * ssc[c0 + j] + ssh[c0 + j]));
#pragma unroll
    for (int j = 0; j < 8; ++j)
        ov[8 + j] = f2h_bits(sp(h2f(ip1[j]) * ssc[c0 + 8 + j] + ssh[c0 + 8 + j]));
    *(uint4*)(hact + idx * 16)     = *(uint4*)&ov[0];
    *(uint4*)(hact + idx * 16 + 8) = *(uint4*)&ov[8];
}

// ---------------------------------------------------------------------------
// gather2 [R30]: R28 scalar-control/branch-skip plane, widened to 8 ROWS PER
// HALF (16 rows/block): doubles independent hact-load chains per thread
// (16 in flight) for the latency-bound random-row walk. mdeg = max of 8
// degrees raises loop over-execution, but skipped slots cost only scalar
// branch checks (R28: loads are branch-skipped, never issued).
// ---------------------------------------------------------------------------
__global__ __launch_bounds__(256)
void gather2_kernel(const ushort_t* __restrict__ hact, const uint32_t* __restrict__ elist,
                    const int* __restrict__ start, const int* __restrict__ cnt,
                    const float* __restrict__ ee_l, ushort_t* __restrict__ aggP, int N)
{
    int t = threadIdx.x;
    int d0 = (t & 127) * 2;
    // wave-uniform first row of this half (t>>7 is uniform within a wave)
    int ib = __builtin_amdgcn_readfirstlane(blockIdx.x * 16 + (t >> 7) * 8);
    float2 e0 = *(const float2*)(ee_l + d0);        // bond 0 pair
    float2 e1 = *(const float2*)(ee_l + D_ + d0);   // bond 1 / self-loop pair
    int sbase[8], sdeg[8];
    float ax[8], ay[8];
    int mdeg = 0;
#pragma unroll
    for (int r = 0; r < 8; ++r) {
        int i = ib + r;
        sbase[r] = 0; sdeg[r] = 0; ax[r] = 0.f; ay[r] = 0.f;
        if (i < N) {                       // uniform branch
            sbase[r] = start[i];           // scalar addr -> s_load
            sdeg[r]  = cnt[i];
            uint32_t hv = *(const uint32_t*)(hact + (size_t)i * D_ + d0);
            ax[r] = h2f((ushort_t)hv) + e1.x;
            ay[r] = h2f((ushort_t)(hv >> 16)) + e1.y;
            mdeg = (sdeg[r] > mdeg) ? sdeg[r] : mdeg;
        }
    }
    for (int j = 0; j < mdeg; j += 2) {
        uint32_t pA[8], pB[8];
#pragma unroll
        for (int r = 0; r < 8; ++r) {      // guarded scalar loads (s_cbranch)
            if (j     < sdeg[r]) pA[r] = elist[sbase[r] + j];
            if (j + 1 < sdeg[r]) pB[r] = elist[sbase[r] + j + 1];
        }
        uint32_t hvA[8], hvB[8];
#pragma unroll
        for (int r = 0; r < 8; ++r)        // guarded vector loads, batched issue
            if (j < sdeg[r])
                hvA[r] = *(const uint32_t*)(hact + (size_t)(pA[r] & 0x3FFFFFFF) * D_ + d0);
#pragma unroll
        for (int r = 0; r < 8; ++r)
            if (j + 1 < sdeg[r])
                hvB[r] = *(const uint32_t*)(hact + (size_t)(pB[r] & 0x3FFFFFFF) * D_ + d0);
#pragma unroll
        for (int r = 0; r < 8; ++r) {
            if (j < sdeg[r]) {             // uniform branch
                bool b1 = (pA[r] >> 30) != 0;   // scalar condition
                ax[r] += h2f((ushort_t)hvA[r]) + (b1 ? e1.x : e0.x);
                ay[r] += h2f((ushort_t)(hvA[r] >> 16)) + (b1 ? e1.y : e0.y);
            }
            if (j + 1 < sdeg[r]) {
                bool b1 = (pB[r] >> 30) != 0;
                ax[r] += h2f((ushort_t)hvB[r]) + (b1 ? e1.x : e0.x);
                ay[r] += h2f((ushort_t)(hvB[r] >> 16)) + (b1 ? e1.y : e0.y);
            }
        }
    }
#pragma unroll
    for (int r = 0; r < 8; ++r) {
        int i = ib + r;
        if (i < N) {
            size_t o = pk_off(i, d0, 8);   // even -> 4B-aligned u32 slot
            *(uint32_t*)(aggP + o) = pk2(ax[r], ay[r]);
        }
    }
}

// ---------------------------------------------------------------------------
// pool_bn [R21]: graph-mean of BN-affine(h16) -> packed f16 (feeds feat gemm).
// ---------------------------------------------------------------------------
__global__ __launch_bounds__(256)
void pool_bn_kernel(const ushort_t* __restrict__ h16, const float* __restrict__ bnsum,
                    const float* __restrict__ gamma, const float* __restrict__ beta,
                    const int* __restrict__ gstart, const int* __restrict__ gend,
                    ushort_t* __restrict__ poolP, float invN)
{
    int g = blockIdx.x;
    int d = threadIdx.x;
    float mean = bnsum[d] * invN;
    float var = bnsum[D_ + d] * invN - mean * mean;
    float sc = gamma[d] * rsqrtf(fmaxf(var, 0.f) + EPS_);
    float sh = beta[d] - mean * sc;
    int s0 = gstart[g], s1 = gend[g];
    float acc = 0.f;
    int i = s0;
    for (; i + 4 <= s1; i += 4) {
        float a0 = h2f(h16[(size_t)(i + 0) * D_ + d]);
        float a1 = h2f(h16[(size_t)(i + 1) * D_ + d]);
        float a2 = h2f(h16[(size_t)(i + 2) * D_ + d]);
        float a3 = h2f(h16[(size_t)(i + 3) * D_ + d]);
        acc += (a0 + a1) + (a2 + a3);
    }
    for (; i < s1; ++i)
        acc += h2f(h16[(size_t)i * D_ + d]);
    int cnt = s1 - s0;
    float mval = (cnt > 0) ? (sc * acc / (float)cnt + sh) : 0.f;
    poolP[pk_off(g, d, 8)] = f2h_bits(mval);
}

// ---------------------------------------------------------------------------
// weight pack (R16): W fp32 [K][N] -> SINGLE f16 tiles (nb, kb), row = col n
// ---------------------------------------------------------------------------
__global__ __launch_bounds__(256)
void convert_w_pack(const float* __restrict__ W, ushort_t* __restrict__ dh,
                    int N, int nKB)
{
    int kb = blockIdx.x, nb = blockIdx.y;
    int n = threadIdx.x >> 1, half = threadIdx.x & 1;
#pragma unroll
    for (int j = 0; j < 2; ++j) {
        int kq = half * 2 + j;
        size_t o = (size_t)(nb * nKB + kb) * TILE_SH + kq * PLANE_SH + n * 8;
#pragma unroll
        for (int jj = 0; jj < 8; ++jj) {
            float w = W[(size_t)(kb * 32 + kq * 8 + jj) * N + nb * 128 + n];
            dh[o + jj] = f2h_bits(w);
        }
    }
}

// ---------------------------------------------------------------------------
// fused_mlp_kernel [R24-proven form — FINAL: R25 col-split, R27 A-in-LDS,
// R29 32-row/2x-occupancy all regressed (R29: hbm_bytes doubled from per-
// block weight refetch + 2x atomics). 106us, MfmaUtil ~21, latency-floored
// at 16 waves/CU]. BOTH layer GEMMs in one kernel; stage-1 operand swap
// (mfma(W1frag, Afrag) -> D = T^T, reg-axis = T-col n) so the T->LDS pack is
// pk2 x2 + ONE 8B store per 4 vals.
// Layout: n = w*64 + nt*16 + kq*4 + rr ->
//   n>>5 = w*2 + (nt>>1); (n>>3)&3 = (nt&1)*2 + (kq>>1); n&7 = (kq&1)*4 + rr.
// ---------------------------------------------------------------------------
__global__ __launch_bounds__(512, 4)
void fused_mlp_kernel(const ushort_t* __restrict__ APK,
                      const ushort_t* __restrict__ W1P,
                      const ushort_t* __restrict__ W2P,
                      const float* __restrict__ b1,
                      const float* __restrict__ b2,
                      ushort_t* __restrict__ Hout,
                      float* __restrict__ bnsum,
                      int m)
{
    __shared__ ushort_t Tl[32768];   // 64 rows x 512 cols packed f16 = 64 KB

    int rb = blockIdx.x;             // 64-row block
    int tid = threadIdx.x, w = tid >> 6, lane = tid & 63;
    int fr = lane & 15, kq = lane >> 4;

    // ---- stage 1 (swapped): T cols [w*64, w*64+64), rows rb*64..+64 ----
    const ushort_t* aT = APK + (size_t)(rb >> 1) * (8 * TILE_SH)
                       + (size_t)kq * PLANE_SH + (size_t)((rb & 1) * 64 + fr) * 8;
    const ushort_t* bT = W1P + (size_t)(w >> 1) * (8 * TILE_SH)
                       + (size_t)kq * PLANE_SH + (size_t)((w & 1) * 64 + fr) * 8;

    f4v acc1[4][4];   // [nt][mt]
#pragma unroll
    for (int i = 0; i < 4; ++i)
#pragma unroll
        for (int j = 0; j < 4; ++j)
            acc1[i][j] = (f4v){0.f, 0.f, 0.f, 0.f};

    for (int kb = 0; kb < 8; ++kb) {
        h8v Af[4], Wf[4];
#pragma unroll
        for (int t = 0; t < 4; ++t) {
            Af[t] = *(const h8v*)(aT + (size_t)kb * TILE_SH + t * 128);
            Wf[t] = *(const h8v*)(bT + (size_t)kb * TILE_SH + t * 128);
        }
        __builtin_amdgcn_s_setprio(1);
#pragma unroll
        for (int nt = 0; nt < 4; ++nt)
#pragma unroll
            for (int mt = 0; mt < 4; ++mt)
                acc1[nt][mt] = __builtin_amdgcn_mfma_f32_16x16x32_f16(
                    Wf[nt], Af[mt], acc1[nt][mt], 0, 0, 0);
        __builtin_amdgcn_s_setprio(0);
    }

    // T -> LDS: lane holds T[m = mt*16+fr][n = w*64 + nt*16 + kq*4 + rr].
#pragma unroll
    for (int nt = 0; nt < 4; ++nt) {
        float4 b1v = *(const float4*)(b1 + w * 64 + nt * 16 + kq * 4);
        int baseu = (w * 2 + (nt >> 1)) * 2048
                  + ((nt & 1) * 2 + (kq >> 1)) * 512
                  + (kq & 1) * 4;
#pragma unroll
        for (int mt = 0; mt < 4; ++mt) {
            uint2 val;
            val.x = pk2(sp(acc1[nt][mt][0] + b1v.x), sp(acc1[nt][mt][1] + b1v.y));
            val.y = pk2(sp(acc1[nt][mt][2] + b1v.z), sp(acc1[nt][mt][3] + b1v.w));
            *(uint2*)(Tl + baseu + (mt * 16 + fr) * 8) = val;
        }
    }
    __syncthreads();

    // ---- stage 2: cols [w*32, w*32+32) of 256 ----
    const ushort_t* wT = W2P + (size_t)(w >> 2) * (16 * TILE_SH)
                       + (size_t)kq * PLANE_SH + (size_t)((w & 3) * 32 + fr) * 8;

    f4v acc2[4][2];
#pragma unroll
    for (int i = 0; i < 4; ++i)
#pragma unroll
        for (int j = 0; j < 2; ++j)
            acc2[i][j] = (f4v){0.f, 0.f, 0.f, 0.f};

    for (int kb = 0; kb < 16; ++kb) {
        h8v Tf[4], Wf[2];
#pragma unroll
        for (int t = 0; t < 4; ++t)
            Tf[t] = *(const h8v*)(Tl + kb * 2048 + kq * 512 + (fr + t * 16) * 8);
#pragma unroll
        for (int t = 0; t < 2; ++t)
            Wf[t] = *(const h8v*)(wT + (size_t)kb * TILE_SH + t * 128);
        __builtin_amdgcn_s_setprio(1);
#pragma unroll
        for (int rt = 0; rt < 4; ++rt)
#pragma unroll
            for (int ct = 0; ct < 2; ++ct)
                acc2[rt][ct] = __builtin_amdgcn_mfma_f32_16x16x32_f16(
                    Tf[rt], Wf[ct], acc2[rt][ct], 0, 0, 0);
        __builtin_amdgcn_s_setprio(0);
    }

    // ---- epilogue: row-major f16 h + bn partial sums ----
    int gm0 = rb * 64 + kq * 4;
#pragma unroll
    for (int ct = 0; ct < 2; ++ct) {
        int gn = w * 32 + ct * 16 + fr;
        float bv = b2[gn];
        float s = 0.f, ss = 0.f;
#pragma unroll
        for (int rt = 0; rt < 4; ++rt)
#pragma unroll
            for (int rr = 0; rr < 4; ++rr) {
                int gm = gm0 + rt * 16 + rr;
                if (gm < m) {
                    float v = acc2[rt][ct][rr] + bv;
                    Hout[(size_t)gm * D_ + gn] = f2h_bits(v);
                    s += v;
                    ss += v * v;
                }
            }
        s  += __shfl_xor(s, 16);  s  += __shfl_xor(s, 32);
        ss += __shfl_xor(ss, 16); ss += __shfl_xor(ss, 32);
        if (kq == 0) {
            atomicAdd(&bnsum[gn], s);
            atomicAdd(&bnsum[D_ + gn], ss);
        }
    }
}

// ---------------------------------------------------------------------------
// gemm_p16<EPI> [R19 form]  EPI 3: fp32 row-major Cout = A@B + bias (no act)
// ---------------------------------------------------------------------------
template <int EPI>
__global__ __launch_bounds__(256, 3)
void gemm_p16(const ushort_t* __restrict__ APK, const ushort_t* __restrict__ BPK,
              const float* __restrict__ bias,
              ushort_t* __restrict__ Tout, float* __restrict__ Cout,
              float* __restrict__ bnsum, const int* __restrict__ batch,
              int m, int N, int nKB)
{
    const int NB = N >> 7;
    const int mb = (m + 127) >> 7;
    int id = blockIdx.x;
    int grp = id / (8 * NB);
    int rem = id - grp * 8 * NB;
    int nb = rem >> 3;
    int rb = grp * 8 + (rem & 7);
    if (rb >= mb) return;   // uniform early-out (tail row-group)

    int tid = threadIdx.x, wave = tid >> 6, lane = tid & 63;
    int wr = wave >> 1, wc = wave & 1;
    int fr = lane & 15, kq = lane >> 4;

    const ushort_t* aP = APK + (size_t)rb * nKB * TILE_SH
                       + (size_t)kq * PLANE_SH + (size_t)(wr * 64 + fr) * 8;
    const ushort_t* bP = BPK + (size_t)nb * nKB * TILE_SH
                       + (size_t)kq * PLANE_SH + (size_t)(wc * 64 + fr) * 8;

    f4v acc[4][4];
#pragma unroll
    for (int i = 0; i < 4; ++i)
#pragma unroll
        for (int j = 0; j < 4; ++j)
            acc[i][j] = (f4v){0.f, 0.f, 0.f, 0.f};

    h8v Fa[4], Fb[4], Ga[4], Gb[4];

#define LOADF(dA, dB, kbi)                                                   \
    {   const ushort_t* ap_ = aP + (size_t)(kbi) * TILE_SH;                  \
        const ushort_t* bp_ = bP + (size_t)(kbi) * TILE_SH;                  \
        _Pragma("unroll")                                                    \
        for (int t = 0; t < 4; ++t) {                                        \
            dA[t] = *(const h8v*)(ap_ + t * 128);                            \
            dB[t] = *(const h8v*)(bp_ + t * 128);                            \
        } }

#define MFMA16(sA, sB)                                                       \
    {   __builtin_amdgcn_s_setprio(1);                                       \
        _Pragma("unroll")                                                    \
        for (int rt = 0; rt < 4; ++rt)                                       \
            _Pragma("unroll")                                                \
            for (int ct = 0; ct < 4; ++ct)                                   \
                acc[rt][ct] = __builtin_amdgcn_mfma_f32_16x16x32_f16(        \
                    sA[rt], sB[ct], acc[rt][ct], 0, 0, 0);                   \
        __builtin_amdgcn_s_setprio(0); }

    LOADF(Fa, Fb, 0);
    for (int kb = 0; kb < nKB; kb += 2) {
        LOADF(Ga, Gb, kb + 1);
        MFMA16(Fa, Fb);
        if (kb + 2 < nKB) LOADF(Fa, Fb, kb + 2);
        MFMA16(Ga, Gb);
    }
#undef LOADF
#undef MFMA16

    int gm00 = rb * 128 + wr * 64 + kq * 4;
    int gn0  = nb * 128 + wc * 64 + fr;
    int nKBo = N >> 5;
    size_t tileRow = (size_t)(rb * nKBo + nb * 4 + wc * 2) * TILE_SH
                   + (size_t)((wr * 64 + kq * 4) * 8 + (fr & 7));
#pragma unroll
    for (int ct = 0; ct < 4; ++ct) {
        int gn = gn0 + ct * 16;
        float bv = bias[gn];
        float s = 0.f, ss = 0.f;
        size_t cb = tileRow + (size_t)(ct >> 1) * TILE_SH
                  + (size_t)((2 * ct + (fr >> 3)) & 3) * PLANE_SH;
#pragma unroll
        for (int rt = 0; rt < 4; ++rt) {
            if (EPI == 2) {
                int bp = -1; float run = 0.f;
#pragma unroll
                for (int rr = 0; rr < 4; ++rr) {
                    int gm = gm00 + rt * 16 + rr;
                    if (gm >= m) continue;
                    float v = acc[rt][ct][rr] + bv;
                    int bg = batch[gm];
                    if (bg == bp) { run += v; }
                    else {
                        if (bp >= 0) atomicAdd(&Cout[(size_t)bp * N + gn], run);
                        bp = bg; run = v;
                    }
                }
                if (bp >= 0) atomicAdd(&Cout[(size_t)bp * N + gn], run);
            } else {
#pragma unroll
                for (int rr = 0; rr < 4; ++rr) {
                    int gm = gm00 + rt * 16 + rr;
                    if (gm >= m) continue;
                    float v = acc[rt][ct][rr] + bv;
                    if (EPI == 0) {
                        Tout[cb + (rt * 16 + rr) * 8] = f2h_bits(sp(v));
                    } else if (EPI == 1) {
                        Tout[(size_t)gm * N + gn] = f2h_bits(v);
                        s += v;
                        ss += v * v;
                    } else {  // EPI == 3: fp32 row-major, no activation
                        Cout[(size_t)gm * N + gn] = v;
                    }
                }
            }
        }
        if (EPI == 1) {
            s  += __shfl_xor(s, 16);  s  += __shfl_xor(s, 32);
            ss += __shfl_xor(ss, 16); ss += __shfl_xor(ss, 32);
            if (kq == 0) {
                atomicAdd(&bnsum[gn], s);
                atomicAdd(&bnsum[D_ + gn], ss);
            }
        }
    }
}

// ---------------------------------------------------------------------------
// fp32 GEMM for the small head: C = softplus(A @ W + bias)
// ---------------------------------------------------------------------------
#define BM 64
#define BN 64
#define BK 16

__global__ __launch_bounds__(256)
void gemm_head(const float* __restrict__ A, const float* __restrict__ W,
               const float* __restrict__ bias, float* __restrict__ C,
               int M, int N, int K)
{
    __shared__ float As[BK][BM + 4];
    __shared__ float Ws[BK][BN + 4];

    int tid = threadIdx.x;
    int bm = blockIdx.y * BM;
    int bn = blockIdx.x * BN;
    int tx = tid & 15;
    int ty = tid >> 4;

    float acc[4][4] = {};

    int a_m = tid >> 2;
    int a_k = (tid & 3) * 4;
    int w_k = tid >> 4;
    int w_n = (tid & 15) * 4;

    for (int k0 = 0; k0 < K; k0 += BK) {
        int gm = bm + a_m;
        float4 av = make_float4(0.f, 0.f, 0.f, 0.f);
        if (gm < M)
            av = *(const float4*)(A + (size_t)gm * K + k0 + a_k);
        As[a_k + 0][a_m] = av.x;
        As[a_k + 1][a_m] = av.y;
        As[a_k + 2][a_m] = av.z;
        As[a_k + 3][a_m] = av.w;

        float4 wv = *(const float4*)(W + (size_t)(k0 + w_k) * N + bn + w_n);
        *(float4*)&Ws[w_k][w_n] = wv;

        __syncthreads();

#pragma unroll
        for (int k = 0; k < BK; ++k) {
            float4 a4 = *(const float4*)&As[k][ty * 4];
            float4 b4 = *(const float4*)&Ws[k][tx * 4];
            float a[4] = {a4.x, a4.y, a4.z, a4.w};
            float b[4] = {b4.x, b4.y, b4.z, b4.w};
#pragma unroll
            for (int i = 0; i < 4; ++i)
#pragma unroll
                for (int j = 0; j < 4; ++j)
                    acc[i][j] += a[i] * b[j];
        }
        __syncthreads();
    }

#pragma unroll
    for (int i = 0; i < 4; ++i) {
        int gm = bm + ty * 4 + i;
        if (gm >= M) continue;
#pragma unroll
        for (int j = 0; j < 4; ++j) {
            int gn = bn + tx * 4 + j;
            C[(size_t)gm * N + gn] = sp(acc[i][j] + bias[gn]);
        }
    }
}

__global__ __launch_bounds__(256)
void head2_kernel(const float* __restrict__ hid, const float* __restrict__ w2,
                  const float* __restrict__ b2, float* __restrict__ out, int G)
{
    __shared__ float red[256];
    int g = blockIdx.x;
    int t = threadIdx.x;
    float v = hid[(size_t)g * 256 + t] * w2[t];
    red[t] = v;
    __syncthreads();
    for (int s = 128; s > 0; s >>= 1) {
        if (t < s) red[t] += red[t + s];
        __syncthreads();
    }
    if (t == 0) out[g] = red[0] + b2[0];
}

// ---------------------------------------------------------------------------
extern "C" void kernel_launch(void* const* d_in, const int* in_sizes, int n_in,
                              void* d_out, int out_size, void* d_ws, size_t ws_size,
                              hipStream_t stream)
{
    const int N = in_sizes[0];
    const int E = in_sizes[3];
    const int G = out_size;

    const int*   atomics  = (const int*)d_in[0];
    const float* pos      = (const float*)d_in[1];
    const int*   eidx     = (const int*)d_in[2];
    const int*   eattr    = (const int*)d_in[3];
    const int*   batch    = (const int*)d_in[4];
    const float* x_emb1   = (const float*)d_in[5];
    const float* x_emb2_w = (const float*)d_in[6];
    const float* x_emb2_b = (const float*)d_in[7];
    const float* edge_emb = (const float*)d_in[8];
    const float* mlp_w1   = (const float*)d_in[9];
    const float* mlp_b1   = (const float*)d_in[10];
    const float* mlp_w2   = (const float*)d_in[11];
    const float* mlp_b2   = (const float*)d_in[12];
    const float* bn_g     = (const float*)d_in[13];
    const float* bn_b     = (const float*)d_in[14];
    const float* feat_w   = (const float*)d_in[15];
    const float* feat_b   = (const float*)d_in[16];
    const float* head_w1  = (const float*)d_in[17];
    const float* head_b1  = (const float*)d_in[18];
    const float* head_w2  = (const float*)d_in[19];
    const float* head_b2  = (const float*)d_in[20];
    float* out = (float*)d_out;

    const int* src = eidx;
    const int* dst = eidx + E;

    char* ws = (char*)d_ws;
    size_t off = 0;
    auto carve = [&](size_t bytes) {
        void* p = ws + off;
        off += (bytes + 255) & ~(size_t)255;
        return p;
    };

    const int nRB = (N + 127) / 128;           // 128-row tiles
    const int nGB = (G + 127) / 128;           // 128-row tiles of pooled

    // ---- fixed carve (~170 MB) ----
    ushort_t* h16  = (ushort_t*)carve((size_t)N * D_ * 2);             // 51.2 MB
    ushort_t* hact = (ushort_t*)carve((size_t)N * D_ * 2);             // 51.2 MB
    ushort_t* aggP = (ushort_t*)carve((size_t)nRB * 8 * TILE_SH * 2);  // 52.9 MB
    const size_t WTILES = 32 * TILE_SH;
    ushort_t* w1P = (ushort_t*)carve((size_t)L_ * WTILES * 2);
    ushort_t* w2P = (ushort_t*)carve((size_t)L_ * WTILES * 2);
    ushort_t* fP  = (ushort_t*)carve(WTILES * 2);
    float* bnsum  = (float*)carve(2 * D_ * 4);
    float* gfeat  = (float*)carve((size_t)G * FD_ * 4);                // 8.2 MB
    float* hid    = (float*)carve((size_t)G * (FD_ / 2) * 4);
    ushort_t* poolP = (ushort_t*)carve((size_t)nGB * 8 * TILE_SH * 2); // 2.2 MB
    int* gstart  = (int*)carve((size_t)G * 4);
    int* gend    = (int*)carve((size_t)G * 4);
    // CSR buffers (~5 MB)
    int* cnt_i   = (int*)carve((size_t)N * 4);
    int* start_i = (int*)carve((size_t)N * 4);
    int* cursor  = (int*)carve((size_t)N * 4);
    int* total   = (int*)carve(4);
    uint32_t* elist = (uint32_t*)carve((size_t)E * 4);

    const float invN = 1.f / (float)N;

    // ---- CSR build (once per launch, reused all 5 layers) ----
    hipMemsetAsync(cnt_i, 0, (size_t)N * 4, stream);
    hipMemsetAsync(total, 0, 4, stream);
    hipMemsetAsync(gstart, 0, (size_t)G * 4, stream);
    hipMemsetAsync(gend, 0, (size_t)G * 4, stream);
    hist_kernel<<<(E + 255) / 256, 256, 0, stream>>>(dst, cnt_i, E);
    alloc_kernel<<<(N + 255) / 256, 256, 0, stream>>>(cnt_i, start_i, cursor, total, N);
    fill_kernel<<<(E + 255) / 256, 256, 0, stream>>>(src, dst, eattr, cursor, elist, E);
    range_kernel<<<(N + 255) / 256, 256, 0, stream>>>(batch, gstart, gend, N);

    // ---- one-time weight packing (single f16) ----
    for (int l = 0; l < L_; ++l) {
        convert_w_pack<<<dim3(8, 4), 256, 0, stream>>>(
            mlp_w1 + (size_t)l * D_ * FD_, w1P + (size_t)l * WTILES, FD_, 8);
        convert_w_pack<<<dim3(16, 2), 256, 0, stream>>>(
            mlp_w2 + (size_t)l * FD_ * D_, w2P + (size_t)l * WTILES, D_, 16);
    }
    convert_w_pack<<<dim3(8, 4), 256, 0, stream>>>(feat_w, fP, FD_, 8);

    init_h_kernel<<<N, 256, 0, stream>>>(atomics, pos, x_emb1, x_emb2_w, x_emb2_b, h16, N);

    const long long total16 = (long long)N * D_ / 16;
    const int ACTB = (int)((total16 + 255) / 256);
    const int GB16 = (N + 15) / 16;
    const int FB  = (N + 63) / 64;             // fused 64-row blocks

    for (int l = 0; l < L_; ++l) {
        const float* ee_l = edge_emb + (size_t)l * 2 * D_;
        const ushort_t* gsrc = h16;
        if (l > 0) {
            act16_kernel<<<ACTB, 256, 0, stream>>>(h16, hact, bnsum,
                bn_g + (size_t)(l - 1) * D_, bn_b + (size_t)(l - 1) * D_,
                total16, invN);
            gsrc = hact;
        }
        gather2_kernel<<<GB16, 256, 0, stream>>>(gsrc, elist, start_i, cnt_i,
                                                 ee_l, aggP, N);

        hipMemsetAsync(bnsum, 0, 2 * D_ * 4, stream);
        fused_mlp_kernel<<<FB, 512, 0, stream>>>(
            aggP, w1P + (size_t)l * WTILES, w2P + (size_t)l * WTILES,
            mlp_b1 + (size_t)l * FD_, mlp_b2 + (size_t)l * D_,
            h16, bnsum, N);
    }

    // ---- pool-first feat path: gfeat = mean_g(BN(h16)) @ feat_w + feat_b ----
    pool_bn_kernel<<<G, 256, 0, stream>>>(h16, bnsum, bn_g + (size_t)(L_ - 1) * D_,
                                          bn_b + (size_t)(L_ - 1) * D_,
                                          gstart, gend, poolP, invN);
    auto swgrid = [](int mb, int NBc) { return ((mb + 7) / 8) * 8 * NBc; };
    gemm_p16<3><<<swgrid(nGB, 4), 256, 0, stream>>>(
        poolP, fP, feat_b, nullptr, gfeat, nullptr, nullptr, G, FD_, 8);

    // ---- head ----
    gemm_head<<<dim3((FD_ / 2) / BN, (G + BM - 1) / BM), 256, 0, stream>>>(
        gfeat, head_w1, head_b1, hid, G, FD_ / 2, FD_);
    head2_kernel<<<G, 256, 0, stream>>>(hid, head_w2, head_b2, out, G);
}

// Round 14
// 1063.731 us; speedup vs baseline: 1.1377x; 1.0704x over previous
//
#include <hip/hip_runtime.h>
#include <hip/hip_bf16.h>
#include <hip/hip_fp16.h>
#include <stdint.h>

#define D_  256   // emb dim
#define FD_ 512   // feat dim
#define L_  5     // layers
#define EPS_ 1e-5f

// packed-tile format (R6-proven): tile = 128 rows x 32 k, stored as 4 k-planes
// (8 k each): plane = 128 rows x 16B + 64B pad = 2112B. tile = 8448B = 4224 sh.
#define PLANE_SH 1056
#define TILE_SH  4224

typedef unsigned short ushort_t;
typedef __attribute__((ext_vector_type(8))) _Float16 h8v;  // 8 f16 (MFMA frag)
typedef __attribute__((ext_vector_type(4))) float    f4v;  // MFMA C/D frag

// numerically-stable softplus == jnp.logaddexp(x, 0) — NATIVE exp/log (R11-proven)
__device__ __forceinline__ float sp(float x) {
    float t = __expf(-fabsf(x));            // native v_exp_f32
    return fmaxf(x, 0.f) + __logf(1.f + t); // native v_log_f32
}

__device__ __forceinline__ ushort_t f2h_bits(float v) {
    union { _Float16 h; ushort_t u; } c;
    c.h = (_Float16)v;
    return c.u;
}

__device__ __forceinline__ float h2f(ushort_t u) {
    union { ushort_t u; _Float16 h; } c;
    c.u = u;
    return (float)c.h;
}

// two f32 -> one u32 of 2xf16 (RTNE, matches f2h_bits everywhere else)
__device__ __forceinline__ uint32_t pk2(float a, float b) {
    return (uint32_t)f2h_bits(a) | ((uint32_t)f2h_bits(b) << 16);
}

// packed-f16 element offset for (row gm, col gn) with nKB = cols/32
__device__ __forceinline__ size_t pk_off(int gm, int gn, int nKB) {
    return ((size_t)(gm >> 7) * nKB + (gn >> 5)) * TILE_SH
         + (size_t)((gn >> 3) & 3) * PLANE_SH
         + (gm & 127) * 8 + (gn & 7);
}

// ---------------------------------------------------------------------------
// h16[i,d] = f16( x_emb1[atomics[i],d] + pos[i,:] @ x_emb2_w[:,d] + x_emb2_b[d] )
// ---------------------------------------------------------------------------
__global__ __launch_bounds__(256)
void init_h_kernel(const int* __restrict__ atomics, const float* __restrict__ pos,
                   const float* __restrict__ emb1, const float* __restrict__ w2,
                   const float* __restrict__ b2, ushort_t* __restrict__ h16, int N)
{
    int i = blockIdx.x;
    int d = threadIdx.x;
    int a = atomics[i];
    float p0 = pos[(size_t)i * 3 + 0];
    float p1 = pos[(size_t)i * 3 + 1];
    float p2 = pos[(size_t)i * 3 + 2];
    float v = emb1[(size_t)a * D_ + d]
            + p0 * w2[0 * D_ + d]
            + p1 * w2[1 * D_ + d]
            + p2 * w2[2 * D_ + d]
            + b2[d];
    h16[(size_t)i * D_ + d] = f2h_bits(v);
}

// ---------------------------------------------------------------------------
// CSR build (unordered segments; segment order irrelevant)
// ---------------------------------------------------------------------------
__global__ __launch_bounds__(256)
void hist_kernel(const int* __restrict__ dst, int* __restrict__ cnt, int E)
{
    int e = blockIdx.x * 256 + threadIdx.x;
    if (e < E) atomicAdd(&cnt[dst[e]], 1);
}

__global__ __launch_bounds__(256)
void alloc_kernel(const int* __restrict__ cnt, int* __restrict__ start,
                  int* __restrict__ cursor, int* __restrict__ total, int N)
{
    int i = blockIdx.x * 256 + threadIdx.x;
    if (i < N) {
        int s = atomicAdd(total, cnt[i]);
        start[i] = s;
        cursor[i] = s;
    }
}

__global__ __launch_bounds__(256)
void fill_kernel(const int* __restrict__ src, const int* __restrict__ dst,
                 const int* __restrict__ attr, int* __restrict__ cursor,
                 uint32_t* __restrict__ elist, int E)
{
    int e = blockIdx.x * 256 + threadIdx.x;
    if (e < E) {
        int p = atomicAdd(&cursor[dst[e]], 1);
        elist[p] = (uint32_t)src[e] | ((uint32_t)attr[e] << 30);
    }
}

// ---------------------------------------------------------------------------
// graph node ranges (batch is sorted): gstart[g]..gend[g]
// ---------------------------------------------------------------------------
__global__ __launch_bounds__(256)
void range_kernel(const int* __restrict__ batch, int* __restrict__ gstart,
                  int* __restrict__ gend, int N)
{
    int i = blockIdx.x * 256 + threadIdx.x;
    if (i >= N) return;
    int b = batch[i];
    if (i == 0 || batch[i - 1] != b) gstart[b] = i;
    if (i == N - 1 || batch[i + 1] != b) gend[b] = i + 1;
}

// ---------------------------------------------------------------------------
// act16 [R24]: hact = f16( sp( BN-affine(h16) ) ), 16 ch/thread (32B loads)
// ---------------------------------------------------------------------------
__global__ __launch_bounds__(256)
void act16_kernel(const ushort_t* __restrict__ h16, ushort_t* __restrict__ hact,
                  const float* __restrict__ bnsum, const float* __restrict__ gamma,
                  const float* __restrict__ beta, long long total16, float invN)
{
    __shared__ float ssc[256], ssh[256];
    int t = threadIdx.x;
    {
        float mean = bnsum[t] * invN;
        float var = bnsum[D_ + t] * invN - mean * mean;
        float sc = gamma[t] * rsqrtf(fmaxf(var, 0.f) + EPS_);
        ssc[t] = sc;
        ssh[t] = beta[t] - mean * sc;
    }
    __syncthreads();
    long long idx = (long long)blockIdx.x * 256 + t;
    if (idx >= total16) return;
    int c0 = (int)((idx * 16) & 255);
    uint4 in0 = *(const uint4*)(h16 + idx * 16);
    uint4 in1 = *(const uint4*)(h16 + idx * 16 + 8);
    ushort_t* ip0 = (ushort_t*)&in0;
    ushort_t* ip1 = (ushort_t*)&in1;
    ushort_t ov[16];
#pragma unroll
    for (int j = 0; j < 8; ++j)
        ov[j] = f2h_bits(sp(h2f(ip0[j]) * ssc[c0 + j] + ssh[c0 + j]));
#pragma unroll
    for (int j = 0; j < 8; ++j)
        ov[8 + j] = f2h_bits(sp(h2f(ip1[j]) * ssc[c0 + 8 + j] + ssh[c0 + 8 + j]));
    *(uint4*)(hact + idx * 16)     = *(uint4*)&ov[0];
    *(uint4*)(hact + idx * 16 + 8) = *(uint4*)&ov[8];
}

// ---------------------------------------------------------------------------
// gather2 [R28-proven FINAL]: scalar control plane + branch-skipped loads,
// 8 rows/block (4 per half). R30's 16-row widening regressed (mdeg=max-of-8
// over-execution > ILP gain) -> this is gather2's converged form.
// ---------------------------------------------------------------------------
__global__ __launch_bounds__(256)
void gather2_kernel(const ushort_t* __restrict__ hact, const uint32_t* __restrict__ elist,
                    const int* __restrict__ start, const int* __restrict__ cnt,
                    const float* __restrict__ ee_l, ushort_t* __restrict__ aggP, int N)
{
    int t = threadIdx.x;
    int d0 = (t & 127) * 2;
    // wave-uniform first row of this half (t>>7 is uniform within a wave)
    int ib = __builtin_amdgcn_readfirstlane(blockIdx.x * 8 + (t >> 7) * 4);
    float2 e0 = *(const float2*)(ee_l + d0);        // bond 0 pair
    float2 e1 = *(const float2*)(ee_l + D_ + d0);   // bond 1 / self-loop pair
    int sbase[4], sdeg[4];
    float ax[4], ay[4];
    int mdeg = 0;
#pragma unroll
    for (int r = 0; r < 4; ++r) {
        int i = ib + r;
        sbase[r] = 0; sdeg[r] = 0; ax[r] = 0.f; ay[r] = 0.f;
        if (i < N) {                       // uniform branch
            sbase[r] = start[i];           // scalar addr -> s_load
            sdeg[r]  = cnt[i];
            uint32_t hv = *(const uint32_t*)(hact + (size_t)i * D_ + d0);
            ax[r] = h2f((ushort_t)hv) + e1.x;
            ay[r] = h2f((ushort_t)(hv >> 16)) + e1.y;
            mdeg = (sdeg[r] > mdeg) ? sdeg[r] : mdeg;
        }
    }
    for (int j = 0; j < mdeg; j += 2) {
        uint32_t pA[4], pB[4];
#pragma unroll
        for (int r = 0; r < 4; ++r) {      // guarded scalar loads (s_cbranch)
            if (j     < sdeg[r]) pA[r] = elist[sbase[r] + j];
            if (j + 1 < sdeg[r]) pB[r] = elist[sbase[r] + j + 1];
        }
        uint32_t hvA[4], hvB[4];
#pragma unroll
        for (int r = 0; r < 4; ++r)        // guarded vector loads, batched issue
            if (j < sdeg[r])
                hvA[r] = *(const uint32_t*)(hact + (size_t)(pA[r] & 0x3FFFFFFF) * D_ + d0);
#pragma unroll
        for (int r = 0; r < 4; ++r)
            if (j + 1 < sdeg[r])
                hvB[r] = *(const uint32_t*)(hact + (size_t)(pB[r] & 0x3FFFFFFF) * D_ + d0);
#pragma unroll
        for (int r = 0; r < 4; ++r) {
            if (j < sdeg[r]) {             // uniform branch
                bool b1 = (pA[r] >> 30) != 0;   // scalar condition
                ax[r] += h2f((ushort_t)hvA[r]) + (b1 ? e1.x : e0.x);
                ay[r] += h2f((ushort_t)(hvA[r] >> 16)) + (b1 ? e1.y : e0.y);
            }
            if (j + 1 < sdeg[r]) {
                bool b1 = (pB[r] >> 30) != 0;
                ax[r] += h2f((ushort_t)hvB[r]) + (b1 ? e1.x : e0.x);
                ay[r] += h2f((ushort_t)(hvB[r] >> 16)) + (b1 ? e1.y : e0.y);
            }
        }
    }
#pragma unroll
    for (int r = 0; r < 4; ++r) {
        int i = ib + r;
        if (i < N) {
            size_t o = pk_off(i, d0, 8);   // even -> 4B-aligned u32 slot
            *(uint32_t*)(aggP + o) = pk2(ax[r], ay[r]);
        }
    }
}

// ---------------------------------------------------------------------------
// pool_bn [R21]: graph-mean of BN-affine(h16) -> packed f16 (feeds feat gemm).
// ---------------------------------------------------------------------------
__global__ __launch_bounds__(256)
void pool_bn_kernel(const ushort_t* __restrict__ h16, const float* __restrict__ bnsum,
                    const float* __restrict__ gamma, const float* __restrict__ beta,
                    const int* __restrict__ gstart, const int* __restrict__ gend,
                    ushort_t* __restrict__ poolP, float invN)
{
    int g = blockIdx.x;
    int d = threadIdx.x;
    float mean = bnsum[d] * invN;
    float var = bnsum[D_ + d] * invN - mean * mean;
    float sc = gamma[d] * rsqrtf(fmaxf(var, 0.f) + EPS_);
    float sh = beta[d] - mean * sc;
    int s0 = gstart[g], s1 = gend[g];
    float acc = 0.f;
    int i = s0;
    for (; i + 4 <= s1; i += 4) {
        float a0 = h2f(h16[(size_t)(i + 0) * D_ + d]);
        float a1 = h2f(h16[(size_t)(i + 1) * D_ + d]);
        float a2 = h2f(h16[(size_t)(i + 2) * D_ + d]);
        float a3 = h2f(h16[(size_t)(i + 3) * D_ + d]);
        acc += (a0 + a1) + (a2 + a3);
    }
    for (; i < s1; ++i)
        acc += h2f(h16[(size_t)i * D_ + d]);
    int cnt = s1 - s0;
    float mval = (cnt > 0) ? (sc * acc / (float)cnt + sh) : 0.f;
    poolP[pk_off(g, d, 8)] = f2h_bits(mval);
}

// ---------------------------------------------------------------------------
// weight pack (R16): W fp32 [K][N] -> SINGLE f16 tiles (nb, kb), row = col n
// ---------------------------------------------------------------------------
__global__ __launch_bounds__(256)
void convert_w_pack(const float* __restrict__ W, ushort_t* __restrict__ dh,
                    int N, int nKB)
{
    int kb = blockIdx.x, nb = blockIdx.y;
    int n = threadIdx.x >> 1, half = threadIdx.x & 1;
#pragma unroll
    for (int j = 0; j < 2; ++j) {
        int kq = half * 2 + j;
        size_t o = (size_t)(nb * nKB + kb) * TILE_SH + kq * PLANE_SH + n * 8;
#pragma unroll
        for (int jj = 0; jj < 8; ++jj) {
            float w = W[(size_t)(kb * 32 + kq * 8 + jj) * N + nb * 128 + n];
            dh[o + jj] = f2h_bits(w);
        }
    }
}

// ---------------------------------------------------------------------------
// fused_mlp_kernel [R24-proven FINAL: R25 col-split, R27 A-in-LDS, R29
// 32-row/2x-occupancy all regressed]. BOTH layer GEMMs in one kernel;
// stage-1 operand swap (mfma(W1frag, Afrag) -> D = T^T, reg-axis = T-col n)
// so the T->LDS pack is pk2 x2 + ONE 8B store per 4 vals.
// Layout: n = w*64 + nt*16 + kq*4 + rr ->
//   n>>5 = w*2 + (nt>>1); (n>>3)&3 = (nt&1)*2 + (kq>>1); n&7 = (kq&1)*4 + rr.
// ---------------------------------------------------------------------------
__global__ __launch_bounds__(512, 4)
void fused_mlp_kernel(const ushort_t* __restrict__ APK,
                      const ushort_t* __restrict__ W1P,
                      const ushort_t* __restrict__ W2P,
                      const float* __restrict__ b1,
                      const float* __restrict__ b2,
                      ushort_t* __restrict__ Hout,
                      float* __restrict__ bnsum,
                      int m)
{
    __shared__ ushort_t Tl[32768];   // 64 rows x 512 cols packed f16 = 64 KB

    int rb = blockIdx.x;             // 64-row block
    int tid = threadIdx.x, w = tid >> 6, lane = tid & 63;
    int fr = lane & 15, kq = lane >> 4;

    // ---- stage 1 (swapped): T cols [w*64, w*64+64), rows rb*64..+64 ----
    const ushort_t* aT = APK + (size_t)(rb >> 1) * (8 * TILE_SH)
                       + (size_t)kq * PLANE_SH + (size_t)((rb & 1) * 64 + fr) * 8;
    const ushort_t* bT = W1P + (size_t)(w >> 1) * (8 * TILE_SH)
                       + (size_t)kq * PLANE_SH + (size_t)((w & 1) * 64 + fr) * 8;

    f4v acc1[4][4];   // [nt][mt]
#pragma unroll
    for (int i = 0; i < 4; ++i)
#pragma unroll
        for (int j = 0; j < 4; ++j)
            acc1[i][j] = (f4v){0.f, 0.f, 0.f, 0.f};

    for (int kb = 0; kb < 8; ++kb) {
        h8v Af[4], Wf[4];
#pragma unroll
        for (int t = 0; t < 4; ++t) {
            Af[t] = *(const h8v*)(aT + (size_t)kb * TILE_SH + t * 128);
            Wf[t] = *(const h8v*)(bT + (size_t)kb * TILE_SH + t * 128);
        }
        __builtin_amdgcn_s_setprio(1);
#pragma unroll
        for (int nt = 0; nt < 4; ++nt)
#pragma unroll
            for (int mt = 0; mt < 4; ++mt)
                acc1[nt][mt] = __builtin_amdgcn_mfma_f32_16x16x32_f16(
                    Wf[nt], Af[mt], acc1[nt][mt], 0, 0, 0);
        __builtin_amdgcn_s_setprio(0);
    }

    // T -> LDS: lane holds T[m = mt*16+fr][n = w*64 + nt*16 + kq*4 + rr].
#pragma unroll
    for (int nt = 0; nt < 4; ++nt) {
        float4 b1v = *(const float4*)(b1 + w * 64 + nt * 16 + kq * 4);
        int baseu = (w * 2 + (nt >> 1)) * 2048
                  + ((nt & 1) * 2 + (kq >> 1)) * 512
                  + (kq & 1) * 4;
#pragma unroll
        for (int mt = 0; mt < 4; ++mt) {
            uint2 val;
            val.x = pk2(sp(acc1[nt][mt][0] + b1v.x), sp(acc1[nt][mt][1] + b1v.y));
            val.y = pk2(sp(acc1[nt][mt][2] + b1v.z), sp(acc1[nt][mt][3] + b1v.w));
            *(uint2*)(Tl + baseu + (mt * 16 + fr) * 8) = val;
        }
    }
    __syncthreads();

    // ---- stage 2: cols [w*32, w*32+32) of 256 ----
    const ushort_t* wT = W2P + (size_t)(w >> 2) * (16 * TILE_SH)
                       + (size_t)kq * PLANE_SH + (size_t)((w & 3) * 32 + fr) * 8;

    f4v acc2[4][2];
#pragma unroll
    for (int i = 0; i < 4; ++i)
#pragma unroll
        for (int j = 0; j < 2; ++j)
            acc2[i][j] = (f4v){0.f, 0.f, 0.f, 0.f};

    for (int kb = 0; kb < 16; ++kb) {
        h8v Tf[4], Wf[2];
#pragma unroll
        for (int t = 0; t < 4; ++t)
            Tf[t] = *(const h8v*)(Tl + kb * 2048 + kq * 512 + (fr + t * 16) * 8);
#pragma unroll
        for (int t = 0; t < 2; ++t)
            Wf[t] = *(const h8v*)(wT + (size_t)kb * TILE_SH + t * 128);
        __builtin_amdgcn_s_setprio(1);
#pragma unroll
        for (int rt = 0; rt < 4; ++rt)
#pragma unroll
            for (int ct = 0; ct < 2; ++ct)
                acc2[rt][ct] = __builtin_amdgcn_mfma_f32_16x16x32_f16(
                    Tf[rt], Wf[ct], acc2[rt][ct], 0, 0, 0);
        __builtin_amdgcn_s_setprio(0);
    }

    // ---- epilogue: row-major f16 h + bn partial sums ----
    int gm0 = rb * 64 + kq * 4;
#pragma unroll
    for (int ct = 0; ct < 2; ++ct) {
        int gn = w * 32 + ct * 16 + fr;
        float bv = b2[gn];
        float s = 0.f, ss = 0.f;
#pragma unroll
        for (int rt = 0; rt < 4; ++rt)
#pragma unroll
            for (int rr = 0; rr < 4; ++rr) {
                int gm = gm0 + rt * 16 + rr;
                if (gm < m) {
                    float v = acc2[rt][ct][rr] + bv;
                    Hout[(size_t)gm * D_ + gn] = f2h_bits(v);
                    s += v;
                    ss += v * v;
                }
            }
        s  += __shfl_xor(s, 16);  s  += __shfl_xor(s, 32);
        ss += __shfl_xor(ss, 16); ss += __shfl_xor(ss, 32);
        if (kq == 0) {
            atomicAdd(&bnsum[gn], s);
            atomicAdd(&bnsum[D_ + gn], ss);
        }
    }
}

// ---------------------------------------------------------------------------
// gemm_p16<EPI> [R19 form]  EPI 3: fp32 row-major Cout = A@B + bias (no act)
// ---------------------------------------------------------------------------
template <int EPI>
__global__ __launch_bounds__(256, 3)
void gemm_p16(const ushort_t* __restrict__ APK, const ushort_t* __restrict__ BPK,
              const float* __restrict__ bias,
              ushort_t* __restrict__ Tout, float* __restrict__ Cout,
              float* __restrict__ bnsum, const int* __restrict__ batch,
              int m, int N, int nKB)
{
    const int NB = N >> 7;
    const int mb = (m + 127) >> 7;
    int id = blockIdx.x;
    int grp = id / (8 * NB);
    int rem = id - grp * 8 * NB;
    int nb = rem >> 3;
    int rb = grp * 8 + (rem & 7);
    if (rb >= mb) return;   // uniform early-out (tail row-group)

    int tid = threadIdx.x, wave = tid >> 6, lane = tid & 63;
    int wr = wave >> 1, wc = wave & 1;
    int fr = lane & 15, kq = lane >> 4;

    const ushort_t* aP = APK + (size_t)rb * nKB * TILE_SH
                       + (size_t)kq * PLANE_SH + (size_t)(wr * 64 + fr) * 8;
    const ushort_t* bP = BPK + (size_t)nb * nKB * TILE_SH
                       + (size_t)kq * PLANE_SH + (size_t)(wc * 64 + fr) * 8;

    f4v acc[4][4];
#pragma unroll
    for (int i = 0; i < 4; ++i)
#pragma unroll
        for (int j = 0; j < 4; ++j)
            acc[i][j] = (f4v){0.f, 0.f, 0.f, 0.f};

    h8v Fa[4], Fb[4], Ga[4], Gb[4];

#define LOADF(dA, dB, kbi)                                                   \
    {   const ushort_t* ap_ = aP + (size_t)(kbi) * TILE_SH;                  \
        const ushort_t* bp_ = bP + (size_t)(kbi) * TILE_SH;                  \
        _Pragma("unroll")                                                    \
        for (int t = 0; t < 4; ++t) {                                        \
            dA[t] = *(const h8v*)(ap_ + t * 128);                            \
            dB[t] = *(const h8v*)(bp_ + t * 128);                            \
        } }

#define MFMA16(sA, sB)                                                       \
    {   __builtin_amdgcn_s_setprio(1);                                       \
        _Pragma("unroll")                                                    \
        for (int rt = 0; rt < 4; ++rt)                                       \
            _Pragma("unroll")                                                \
            for (int ct = 0; ct < 4; ++ct)                                   \
                acc[rt][ct] = __builtin_amdgcn_mfma_f32_16x16x32_f16(        \
                    sA[rt], sB[ct], acc[rt][ct], 0, 0, 0);                   \
        __builtin_amdgcn_s_setprio(0); }

    LOADF(Fa, Fb, 0);
    for (int kb = 0; kb < nKB; kb += 2) {
        LOADF(Ga, Gb, kb + 1);
        MFMA16(Fa, Fb);
        if (kb + 2 < nKB) LOADF(Fa, Fb, kb + 2);
        MFMA16(Ga, Gb);
    }
#undef LOADF
#undef MFMA16

    int gm00 = rb * 128 + wr * 64 + kq * 4;
    int gn0  = nb * 128 + wc * 64 + fr;
    int nKBo = N >> 5;
    size_t tileRow = (size_t)(rb * nKBo + nb * 4 + wc * 2) * TILE_SH
                   + (size_t)((wr * 64 + kq * 4) * 8 + (fr & 7));
#pragma unroll
    for (int ct = 0; ct < 4; ++ct) {
        int gn = gn0 + ct * 16;
        float bv = bias[gn];
        float s = 0.f, ss = 0.f;
        size_t cb = tileRow + (size_t)(ct >> 1) * TILE_SH
                  + (size_t)((2 * ct + (fr >> 3)) & 3) * PLANE_SH;
#pragma unroll
        for (int rt = 0; rt < 4; ++rt) {
            if (EPI == 2) {
                int bp = -1; float run = 0.f;
#pragma unroll
                for (int rr = 0; rr < 4; ++rr) {
                    int gm = gm00 + rt * 16 + rr;
                    if (gm >= m) continue;
                    float v = acc[rt][ct][rr] + bv;
                    int bg = batch[gm];
                    if (bg == bp) { run += v; }
                    else {
                        if (bp >= 0) atomicAdd(&Cout[(size_t)bp * N + gn], run);
                        bp = bg; run = v;
                    }
                }
                if (bp >= 0) atomicAdd(&Cout[(size_t)bp * N + gn], run);
            } else {
#pragma unroll
                for (int rr = 0; rr < 4; ++rr) {
                    int gm = gm00 + rt * 16 + rr;
                    if (gm >= m) continue;
                    float v = acc[rt][ct][rr] + bv;
                    if (EPI == 0) {
                        Tout[cb + (rt * 16 + rr) * 8] = f2h_bits(sp(v));
                    } else if (EPI == 1) {
                        Tout[(size_t)gm * N + gn] = f2h_bits(v);
                        s += v;
                        ss += v * v;
                    } else {  // EPI == 3: fp32 row-major, no activation
                        Cout[(size_t)gm * N + gn] = v;
                    }
                }
            }
        }
        if (EPI == 1) {
            s  += __shfl_xor(s, 16);  s  += __shfl_xor(s, 32);
            ss += __shfl_xor(ss, 16); ss += __shfl_xor(ss, 32);
            if (kq == 0) {
                atomicAdd(&bnsum[gn], s);
                atomicAdd(&bnsum[D_ + gn], ss);
            }
        }
    }
}

// ---------------------------------------------------------------------------
// fp32 GEMM for the small head: C = softplus(A @ W + bias)
// ---------------------------------------------------------------------------
#define BM 64
#define BN 64
#define BK 16

__global__ __launch_bounds__(256)
void gemm_head(const float* __restrict__ A, const float* __restrict__ W,
               const float* __restrict__ bias, float* __restrict__ C,
               int M, int N, int K)
{
    __shared__ float As[BK][BM + 4];
    __shared__ float Ws[BK][BN + 4];

    int tid = threadIdx.x;
    int bm = blockIdx.y * BM;
    int bn = blockIdx.x * BN;
    int tx = tid & 15;
    int ty = tid >> 4;

    float acc[4][4] = {};

    int a_m = tid >> 2;
    int a_k = (tid & 3) * 4;
    int w_k = tid >> 4;
    int w_n = (tid & 15) * 4;

    for (int k0 = 0; k0 < K; k0 += BK) {
        int gm = bm + a_m;
        float4 av = make_float4(0.f, 0.f, 0.f, 0.f);
        if (gm < M)
            av = *(const float4*)(A + (size_t)gm * K + k0 + a_k);
        As[a_k + 0][a_m] = av.x;
        As[a_k + 1][a_m] = av.y;
        As[a_k + 2][a_m] = av.z;
        As[a_k + 3][a_m] = av.w;

        float4 wv = *(const float4*)(W + (size_t)(k0 + w_k) * N + bn + w_n);
        *(float4*)&Ws[w_k][w_n] = wv;

        __syncthreads();

#pragma unroll
        for (int k = 0; k < BK; ++k) {
            float4 a4 = *(const float4*)&As[k][ty * 4];
            float4 b4 = *(const float4*)&Ws[k][tx * 4];
            float a[4] = {a4.x, a4.y, a4.z, a4.w};
            float b[4] = {b4.x, b4.y, b4.z, b4.w};
#pragma unroll
            for (int i = 0; i < 4; ++i)
#pragma unroll
                for (int j = 0; j < 4; ++j)
                    acc[i][j] += a[i] * b[j];
        }
        __syncthreads();
    }

#pragma unroll
    for (int i = 0; i < 4; ++i) {
        int gm = bm + ty * 4 + i;
        if (gm >= M) continue;
#pragma unroll
        for (int j = 0; j < 4; ++j) {
            int gn = bn + tx * 4 + j;
            C[(size_t)gm * N + gn] = sp(acc[i][j] + bias[gn]);
        }
    }
}

__global__ __launch_bounds__(256)
void head2_kernel(const float* __restrict__ hid, const float* __restrict__ w2,
                  const float* __restrict__ b2, float* __restrict__ out, int G)
{
    __shared__ float red[256];
    int g = blockIdx.x;
    int t = threadIdx.x;
    float v = hid[(size_t)g * 256 + t] * w2[t];
    red[t] = v;
    __syncthreads();
    for (int s = 128; s > 0; s >>= 1) {
        if (t < s) red[t] += red[t + s];
        __syncthreads();
    }
    if (t == 0) out[g] = red[0] + b2[0];
}

// ---------------------------------------------------------------------------
extern "C" void kernel_launch(void* const* d_in, const int* in_sizes, int n_in,
                              void* d_out, int out_size, void* d_ws, size_t ws_size,
                              hipStream_t stream)
{
    const int N = in_sizes[0];
    const int E = in_sizes[3];
    const int G = out_size;

    const int*   atomics  = (const int*)d_in[0];
    const float* pos      = (const float*)d_in[1];
    const int*   eidx     = (const int*)d_in[2];
    const int*   eattr    = (const int*)d_in[3];
    const int*   batch    = (const int*)d_in[4];
    const float* x_emb1   = (const float*)d_in[5];
    const float* x_emb2_w = (const float*)d_in[6];
    const float* x_emb2_b = (const float*)d_in[7];
    const float* edge_emb = (const float*)d_in[8];
    const float* mlp_w1   = (const float*)d_in[9];
    const float* mlp_b1   = (const float*)d_in[10];
    const float* mlp_w2   = (const float*)d_in[11];
    const float* mlp_b2   = (const float*)d_in[12];
    const float* bn_g     = (const float*)d_in[13];
    const float* bn_b     = (const float*)d_in[14];
    const float* feat_w   = (const float*)d_in[15];
    const float* feat_b   = (const float*)d_in[16];
    const float* head_w1  = (const float*)d_in[17];
    const float* head_b1  = (const float*)d_in[18];
    const float* head_w2  = (const float*)d_in[19];
    const float* head_b2  = (const float*)d_in[20];
    float* out = (float*)d_out;

    const int* src = eidx;
    const int* dst = eidx + E;

    char* ws = (char*)d_ws;
    size_t off = 0;
    auto carve = [&](size_t bytes) {
        void* p = ws + off;
        off += (bytes + 255) & ~(size_t)255;
        return p;
    };

    const int nRB = (N + 127) / 128;           // 128-row tiles
    const int nGB = (G + 127) / 128;           // 128-row tiles of pooled

    // ---- fixed carve (~170 MB) ----
    ushort_t* h16  = (ushort_t*)carve((size_t)N * D_ * 2);             // 51.2 MB
    ushort_t* hact = (ushort_t*)carve((size_t)N * D_ * 2);             // 51.2 MB
    ushort_t* aggP = (ushort_t*)carve((size_t)nRB * 8 * TILE_SH * 2);  // 52.9 MB
    const size_t WTILES = 32 * TILE_SH;
    ushort_t* w1P = (ushort_t*)carve((size_t)L_ * WTILES * 2);
    ushort_t* w2P = (ushort_t*)carve((size_t)L_ * WTILES * 2);
    ushort_t* fP  = (ushort_t*)carve(WTILES * 2);
    float* bnsum  = (float*)carve(2 * D_ * 4);
    float* gfeat  = (float*)carve((size_t)G * FD_ * 4);                // 8.2 MB
    float* hid    = (float*)carve((size_t)G * (FD_ / 2) * 4);
    ushort_t* poolP = (ushort_t*)carve((size_t)nGB * 8 * TILE_SH * 2); // 2.2 MB
    int* gstart  = (int*)carve((size_t)G * 4);
    int* gend    = (int*)carve((size_t)G * 4);
    // CSR buffers (~5 MB)
    int* cnt_i   = (int*)carve((size_t)N * 4);
    int* start_i = (int*)carve((size_t)N * 4);
    int* cursor  = (int*)carve((size_t)N * 4);
    int* total   = (int*)carve(4);
    uint32_t* elist = (uint32_t*)carve((size_t)E * 4);

    const float invN = 1.f / (float)N;

    // ---- CSR build (once per launch, reused all 5 layers) ----
    hipMemsetAsync(cnt_i, 0, (size_t)N * 4, stream);
    hipMemsetAsync(total, 0, 4, stream);
    hipMemsetAsync(gstart, 0, (size_t)G * 4, stream);
    hipMemsetAsync(gend, 0, (size_t)G * 4, stream);
    hist_kernel<<<(E + 255) / 256, 256, 0, stream>>>(dst, cnt_i, E);
    alloc_kernel<<<(N + 255) / 256, 256, 0, stream>>>(cnt_i, start_i, cursor, total, N);
    fill_kernel<<<(E + 255) / 256, 256, 0, stream>>>(src, dst, eattr, cursor, elist, E);
    range_kernel<<<(N + 255) / 256, 256, 0, stream>>>(batch, gstart, gend, N);

    // ---- one-time weight packing (single f16) ----
    for (int l = 0; l < L_; ++l) {
        convert_w_pack<<<dim3(8, 4), 256, 0, stream>>>(
            mlp_w1 + (size_t)l * D_ * FD_, w1P + (size_t)l * WTILES, FD_, 8);
        convert_w_pack<<<dim3(16, 2), 256, 0, stream>>>(
            mlp_w2 + (size_t)l * FD_ * D_, w2P + (size_t)l * WTILES, D_, 16);
    }
    convert_w_pack<<<dim3(8, 4), 256, 0, stream>>>(feat_w, fP, FD_, 8);

    init_h_kernel<<<N, 256, 0, stream>>>(atomics, pos, x_emb1, x_emb2_w, x_emb2_b, h16, N);

    const long long total16 = (long long)N * D_ / 16;
    const int ACTB = (int)((total16 + 255) / 256);
    const int GB8 = (N + 7) / 8;
    const int FB  = (N + 63) / 64;             // fused 64-row blocks

    for (int l = 0; l < L_; ++l) {
        const float* ee_l = edge_emb + (size_t)l * 2 * D_;
        const ushort_t* gsrc = h16;
        if (l > 0) {
            act16_kernel<<<ACTB, 256, 0, stream>>>(h16, hact, bnsum,
                bn_g + (size_t)(l - 1) * D_, bn_b + (size_t)(l - 1) * D_,
                total16, invN);
            gsrc = hact;
        }
        gather2_kernel<<<GB8, 256, 0, stream>>>(gsrc, elist, start_i, cnt_i,
                                                ee_l, aggP, N);

        hipMemsetAsync(bnsum, 0, 2 * D_ * 4, stream);
        fused_mlp_kernel<<<FB, 512, 0, stream>>>(
            aggP, w1P + (size_t)l * WTILES, w2P + (size_t)l * WTILES,
            mlp_b1 + (size_t)l * FD_, mlp_b2 + (size_t)l * D_,
            h16, bnsum, N);
    }

    // ---- pool-first feat path: gfeat = mean_g(BN(h16)) @ feat_w + feat_b ----
    pool_bn_kernel<<<G, 256, 0, stream>>>(h16, bnsum, bn_g + (size_t)(L_ - 1) * D_,
                                          bn_b + (size_t)(L_ - 1) * D_,
                                          gstart, gend, poolP, invN);
    auto swgrid = [](int mb, int NBc) { return ((mb + 7) / 8) * 8 * NBc; };
    gemm_p16<3><<<swgrid(nGB, 4), 256, 0, stream>>>(
        poolP, fP, feat_b, nullptr, gfeat, nullptr, nullptr, G, FD_, 8);

    // ---- head ----
    gemm_head<<<dim3((FD_ / 2) / BN, (G + BM - 1) / BM), 256, 0, stream>>>(
        gfeat, head_w1, head_b1, hid, G, FD_ / 2, FD_);
    head2_kernel<<<G, 256, 0, stream>>>(hid, head_w2, head_b2, out, G);
}